// Round 1
// baseline (333.913 us; speedup 1.0000x reference)
//
#include <hip/hip_runtime.h>
#include <hip/hip_fp16.h>

#define FD 96   // feature dim

typedef _Float16 f16x8 __attribute__((ext_vector_type(8)));
typedef float f32x4 __attribute__((ext_vector_type(4)));

// ---- fp16 pack/unpack helpers (4 halves in an int2) -----------------------
__device__ inline float2 unpack2(int v) {
    __half2 h = *reinterpret_cast<__half2*>(&v);
    return __half22float2(h);
}
__device__ inline int2 pack4(float a, float b, float c, float d) {
    __half2 lo = __floats2half2_rn(a, b);
    __half2 hi = __floats2half2_rn(c, d);
    int2 r;
    r.x = *reinterpret_cast<int*>(&lo);
    r.y = *reinterpret_cast<int*>(&hi);
    return r;
}
// load 4 fp16 (int2) from LDS -> float4
__device__ inline float4 lds_w4(const __half* Wl, int k, int c4) {
    int2 wv = *(const int2*)&Wl[k * FD + c4];
    float2 lo = unpack2(wv.x), hi = unpack2(wv.y);
    return make_float4(lo.x, lo.y, hi.x, hi.y);
}

// ---- shared aggregation body: sum fh rows over one CSR row ----------------
__device__ inline float4 agg_row(const int2* __restrict__ fh,
                                 const int* __restrict__ rowptr,
                                 const int* __restrict__ col,
                                 int n, int c) {
    int beg = rowptr[n], end = rowptr[n + 1];
    float ax = 0.f, ay = 0.f, az = 0.f, aw = 0.f;
    int e = beg;
    for (; e + 8 <= end; e += 8) {
        int s0 = col[e + 0], s1 = col[e + 1], s2 = col[e + 2], s3 = col[e + 3];
        int s4 = col[e + 4], s5 = col[e + 5], s6 = col[e + 6], s7 = col[e + 7];
        int2 r0 = fh[(long)s0 * 24 + c], r1 = fh[(long)s1 * 24 + c];
        int2 r2 = fh[(long)s2 * 24 + c], r3 = fh[(long)s3 * 24 + c];
        int2 r4 = fh[(long)s4 * 24 + c], r5 = fh[(long)s5 * 24 + c];
        int2 r6 = fh[(long)s6 * 24 + c], r7 = fh[(long)s7 * 24 + c];
        float2 l0 = unpack2(r0.x), h0 = unpack2(r0.y);
        float2 l1 = unpack2(r1.x), h1_ = unpack2(r1.y);
        float2 l2 = unpack2(r2.x), h2 = unpack2(r2.y);
        float2 l3 = unpack2(r3.x), h3 = unpack2(r3.y);
        float2 l4 = unpack2(r4.x), h4 = unpack2(r4.y);
        float2 l5 = unpack2(r5.x), h5 = unpack2(r5.y);
        float2 l6 = unpack2(r6.x), h6 = unpack2(r6.y);
        float2 l7 = unpack2(r7.x), h7 = unpack2(r7.y);
        ax += (l0.x + l1.x) + (l2.x + l3.x) + (l4.x + l5.x) + (l6.x + l7.x);
        ay += (l0.y + l1.y) + (l2.y + l3.y) + (l4.y + l5.y) + (l6.y + l7.y);
        az += (h0.x + h1_.x) + (h2.x + h3.x) + (h4.x + h5.x) + (h6.x + h7.x);
        aw += (h0.y + h1_.y) + (h2.y + h3.y) + (h4.y + h5.y) + (h6.y + h7.y);
    }
    for (; e < end; e++) {
        int s = col[e];
        int2 r = fh[(long)s * 24 + c];
        float2 lo = unpack2(r.x), hi = unpack2(r.y);
        ax += lo.x; ay += lo.y; az += hi.x; aw += hi.y;
    }
    return make_float4(ax, ay, az, aw);
}

// ---------------------------------------------------------------------------
// K1: degree histogram + per-edge rank capture (perm). Hub via ballot.
// ---------------------------------------------------------------------------
__global__ void deg_kernel(const int* __restrict__ dst, int E, int HUB,
                           int* __restrict__ counts, int* __restrict__ perm) {
    int e = blockIdx.x * 256 + threadIdx.x;
    int d = (e < E) ? dst[e] : -1;
    bool isHub = (d == HUB);
    unsigned long long m = __ballot(isHub);
    if (isHub) {
        int lane = threadIdx.x & 63;
        int leader = __ffsll((unsigned long long)m) - 1;
        int base = 0;
        if (lane == leader) base = atomicAdd(&counts[HUB], (int)__popcll(m));
        base = __shfl(base, leader);
        unsigned long long below = m & ((1ull << lane) - 1ull);
        perm[e] = base + (int)__popcll(below);
    } else if (d >= 0) {
        perm[e] = atomicAdd(&counts[d], 1);
    }
}

// ---------------------------------------------------------------------------
// K2: single-kernel scan. Block b brute-force sums counts[0..b*1024) (cheap:
// <=4.8 MB total L2 reads over 49 blocks), then scans its own 1024-chunk.
// Emits rowptr[0..N] (incl. rowptr[N]) and dinv (fused).
// ---------------------------------------------------------------------------
__global__ __launch_bounds__(1024)
void scan_kernel(const int* __restrict__ counts, int N,
                 int* __restrict__ rowptr, float* __restrict__ dinv) {
    int t = threadIdx.x, lane = t & 63, wv = t >> 6;
    int base = blockIdx.x * 1024;
    // --- block prefix: sum of counts[0..base) ---
    int pre = 0;
    for (int idx = t; idx < base; idx += 1024) pre += counts[idx];
    #pragma unroll
    for (int off = 32; off; off >>= 1) pre += __shfl_down(pre, off);
    __shared__ int wsA[16];
    __shared__ int preS;
    if (lane == 0) wsA[wv] = pre;
    __syncthreads();
    if (t == 0) {
        int s = 0;
        #pragma unroll
        for (int k = 0; k < 16; k++) s += wsA[k];
        preS = s;
    }
    __syncthreads();
    int blockpre = preS;
    // --- chunk inclusive scan ---
    int i = base + t;
    int v = (i < N) ? counts[i] : 0;
    int x = v;
    #pragma unroll
    for (int off = 1; off < 64; off <<= 1) {
        int u = __shfl_up(x, off);
        if (lane >= off) x += u;
    }
    __shared__ int wsum[16];
    if (lane == 63) wsum[wv] = x;
    __syncthreads();
    if (wv == 0 && lane < 16) {
        int w = wsum[lane];
        #pragma unroll
        for (int off = 1; off < 16; off <<= 1) {
            int u = __shfl_up(w, off);
            if (lane >= off) w += u;
        }
        wsum[lane] = w;
    }
    __syncthreads();
    int waveoff = (wv == 0) ? 0 : wsum[wv - 1];
    if (i <= N) rowptr[i] = blockpre + waveoff + x - v;   // exclusive; i==N => total
    if (i < N) {
        float d = (float)v;
        dinv[i] = (d > 0.f) ? rsqrtf(fmaxf(d, 1.f)) : 0.f;
    }
}

// ---------------------------------------------------------------------------
// K3: prep — fused {CSR col fill} + {xh = fp16(dinv*x)} + {weight convert}.
// Grid sections selected by blockIdx.x range.
// ---------------------------------------------------------------------------
__global__ __launch_bounds__(256)
void prep_kernel(const int* __restrict__ src, const int* __restrict__ dst,
                 const int* __restrict__ perm, const int* __restrict__ rowptr,
                 int E,
                 const float* __restrict__ x, const float* __restrict__ dinv,
                 int N,
                 const float* __restrict__ W1, const float* __restrict__ W2a,
                 const float* __restrict__ W2b,
                 int* __restrict__ col, int2* __restrict__ xh,
                 __half* __restrict__ W1h, __half* __restrict__ Wta,
                 __half* __restrict__ Wtb, int gfill, int gconv) {
    int b = blockIdx.x;
    if (b < gfill) {                       // --- fill CSR col ---
        int e = b * 256 + threadIdx.x;
        if (e >= E) return;
        int d = dst[e];
        col[rowptr[d] + perm[e]] = src[e];
    } else if (b < gfill + gconv) {        // --- convert x -> prescaled fp16 ---
        int i = (b - gfill) * 256 + threadIdx.x;
        if (i >= N * 24) return;
        int n = i / 24;
        float dn = dinv[n];
        float4 a = ((const float4*)x)[i];
        xh[i] = pack4(a.x * dn, a.y * dn, a.z * dn, a.w * dn);
    } else {                               // --- weights: W1h + transposed Wta/Wtb
        int i = (b - gfill - gconv) * 256 + threadIdx.x;
        if (i >= FD * FD) return;
        int n = i / FD, k = i % FD;
        Wta[i] = __float2half(W2a[k * FD + n]);
        Wtb[i] = __float2half(W2b[k * FD + n]);
        W1h[i] = __float2half(W1[i]);
    }
}

// ---------------------------------------------------------------------------
// K4: hub row aggregation: dest[0..95] += dinv[HUB]*sum fh[s] (dest fp32,
// pre-zeroed). 256 blocks x 8 streams, LDS reduce, 96 atomics/block.
// ---------------------------------------------------------------------------
__global__ __launch_bounds__(192)
void hub_kernel(const int2* __restrict__ fh, const float* __restrict__ dinv,
                const int* __restrict__ rowptr, const int* __restrict__ col,
                int HUB, float* __restrict__ dest) {
    int c = threadIdx.x;   // 0..23
    int y = threadIdx.y;   // 0..7
    int beg = rowptr[HUB], end = rowptr[HUB + 1];
    int deg = end - beg;
    int nstr = gridDim.x * 8;
    int sid  = blockIdx.x * 8 + y;
    int chunk = (deg + nstr - 1) / nstr;
    int e  = beg + sid * chunk;
    int e1 = min(e + chunk, end);
    float ax = 0.f, ay = 0.f, az = 0.f, aw = 0.f;
    for (; e + 4 <= e1; e += 4) {
        int s0 = col[e + 0], s1 = col[e + 1], s2 = col[e + 2], s3 = col[e + 3];
        int2 r0 = fh[(long)s0 * 24 + c], r1 = fh[(long)s1 * 24 + c];
        int2 r2 = fh[(long)s2 * 24 + c], r3 = fh[(long)s3 * 24 + c];
        float2 l0 = unpack2(r0.x), h0 = unpack2(r0.y);
        float2 l1 = unpack2(r1.x), h1_ = unpack2(r1.y);
        float2 l2 = unpack2(r2.x), h2 = unpack2(r2.y);
        float2 l3 = unpack2(r3.x), h3 = unpack2(r3.y);
        ax += (l0.x + l1.x) + (l2.x + l3.x);
        ay += (l0.y + l1.y) + (l2.y + l3.y);
        az += (h0.x + h1_.x) + (h2.x + h3.x);
        aw += (h0.y + h1_.y) + (h2.y + h3.y);
    }
    for (; e < e1; e++) {
        int s = col[e];
        int2 r = fh[(long)s * 24 + c];
        float2 lo = unpack2(r.x), hi = unpack2(r.y);
        ax += lo.x; ay += lo.y; az += hi.x; aw += hi.y;
    }
    __shared__ float4 red[8][24];
    red[y][c] = make_float4(ax, ay, az, aw);
    __syncthreads();
    if (y == 0) {
        float4 t = red[0][c];
        #pragma unroll
        for (int k = 1; k < 8; k++) {
            float4 u = red[k][c];
            t.x += u.x; t.y += u.y; t.z += u.z; t.w += u.w;
        }
        float dh = dinv[HUB];
        float* o = dest + 4 * c;
        unsafeAtomicAdd(o + 0, t.x * dh);
        unsafeAtomicAdd(o + 1, t.y * dh);
        unsafeAtomicAdd(o + 2, t.z * dh);
        unsafeAtomicAdd(o + 3, t.w * dh);
    }
}

// ---------------------------------------------------------------------------
// K5: agg_gemm1 — fused layer-1: aggregate 64 rows into LDS As (fp32, exact
// pull_kernel math incl. dinv scale), then gemm96_h-identical fp32 x fp16(W)
// FMA GEMM, relu, x dinv -> h1h fp16. Hub row read from hubacc (pre-computed).
// Block (24,16)=384thr=6 waves; each thread aggregates 4 nodes, computes
// 4 rows x 4 cols. LDS: Wl 18432 + As 25600 = 44032 B.
// ---------------------------------------------------------------------------
__global__ __launch_bounds__(384)
void agg_gemm1(const int2* __restrict__ fh, const float* __restrict__ dinv,
               const int* __restrict__ rowptr, const int* __restrict__ col,
               const __half* __restrict__ W1h, const float* __restrict__ bias,
               const float* __restrict__ hubacc, int N, int HUB,
               int2* __restrict__ out16) {
    __shared__ __half Wl[FD * FD];       // 18432 B, [k][n]
    __shared__ float As[64 * 100];       // 25600 B, padded stride 100
    int c = threadIdx.x, y = threadIdx.y;
    int t = y * 24 + c;
    {   // stage W1 fp16 (pre-converted by prep)
        const int4* s = (const int4*)W1h;
        int4* d = (int4*)Wl;
        #pragma unroll
        for (int i = t; i < FD * FD / 8; i += 384) d[i] = s[i];
    }
    int row0 = blockIdx.x * 64;
    for (int j = 0; j < 4; j++) {
        int r = 16 * j + y;
        int n = row0 + r;
        float4 a = make_float4(0.f, 0.f, 0.f, 0.f);
        if (n < N) {
            if (n == HUB) {
                a = *(const float4*)&hubacc[4 * c];      // already x dinv[HUB]
            } else {
                a = agg_row(fh, rowptr, col, n, c);
                float dn = dinv[n];
                a.x *= dn; a.y *= dn; a.z *= dn; a.w *= dn;
            }
        }
        *(float4*)&As[r * 100 + 4 * c] = a;
    }
    __syncthreads();
    // GEMM: thread (c,y) -> rows {y+16*jj}, cols 4c..4c+3 (same fma order as
    // gemm96_h -> bitwise-identical results)
    float acc[4][4];
    #pragma unroll
    for (int jj = 0; jj < 4; jj++)
        #pragma unroll
        for (int i = 0; i < 4; i++) acc[jj][i] = 0.f;
    for (int kk = 0; kk < FD; kk += 4) {
        float4 w0 = lds_w4(Wl, kk + 0, 4 * c);
        float4 w1 = lds_w4(Wl, kk + 1, 4 * c);
        float4 w2 = lds_w4(Wl, kk + 2, 4 * c);
        float4 w3 = lds_w4(Wl, kk + 3, 4 * c);
        #pragma unroll
        for (int jj = 0; jj < 4; jj++) {
            float4 a = *(const float4*)&As[(y + 16 * jj) * 100 + kk];
            acc[jj][0] = fmaf(a.x, w0.x, fmaf(a.y, w1.x, fmaf(a.z, w2.x, fmaf(a.w, w3.x, acc[jj][0]))));
            acc[jj][1] = fmaf(a.x, w0.y, fmaf(a.y, w1.y, fmaf(a.z, w2.y, fmaf(a.w, w3.y, acc[jj][1]))));
            acc[jj][2] = fmaf(a.x, w0.z, fmaf(a.y, w1.z, fmaf(a.z, w2.z, fmaf(a.w, w3.z, acc[jj][2]))));
            acc[jj][3] = fmaf(a.x, w0.w, fmaf(a.y, w1.w, fmaf(a.z, w2.w, fmaf(a.w, w3.w, acc[jj][3]))));
        }
    }
    float4 b4 = *(const float4*)&bias[4 * c];
    #pragma unroll
    for (int jj = 0; jj < 4; jj++) {
        int n = row0 + y + 16 * jj;
        if (n < N) {
            float vx = fmaxf(acc[jj][0] + b4.x, 0.f);
            float vy = fmaxf(acc[jj][1] + b4.y, 0.f);
            float vz = fmaxf(acc[jj][2] + b4.z, 0.f);
            float vw = fmaxf(acc[jj][3] + b4.w, 0.f);
            float dr = dinv[n];
            out16[(long)n * 24 + c] = pack4(vx * dr, vy * dr, vz * dr, vw * dr);
        }
    }
}

// ---------------------------------------------------------------------------
// K6: agg_gemm2 — fused layer-2: aggregate 64 rows -> fp16 LDS As (exact
// pull16 math/rounding), then mfma_dual's verified 16x16x32 dual GEMM from
// LDS. Wt LDS stride padded to 104 halves (kills 8-way bank conflict of the
// old stride-96 reads). Hub row from hubacc (== old pack_hub).
// Block (24,16)=6 waves: wave w owns col-tile w, iterates 4 row-tiles.
// LDS: 2x 96x104x2 + 64x104x2 = 53248 B.
// ---------------------------------------------------------------------------
__global__ __launch_bounds__(384)
void agg_gemm2(const int2* __restrict__ fh, const float* __restrict__ dinv,
               const int* __restrict__ rowptr, const int* __restrict__ col,
               const __half* __restrict__ Wta, const __half* __restrict__ Wtb,
               const float* __restrict__ ba, const float* __restrict__ bb,
               const float* __restrict__ hubacc, int N, int HUB,
               float* __restrict__ mu, float* __restrict__ ls) {
    __shared__ __half WtaL[FD * 104];
    __shared__ __half WtbL[FD * 104];
    __shared__ __half As[64 * 104];
    int c = threadIdx.x, y = threadIdx.y;
    int t = y * 24 + c;
    {   // stage transposed weights into padded rows (12 x 8-half chunks/row)
        #pragma unroll
        for (int i = t; i < FD * 12; i += 384) {
            int n = i / 12, ch = i % 12;
            *(int4*)&WtaL[n * 104 + ch * 8] = *(const int4*)&Wta[n * FD + ch * 8];
            *(int4*)&WtbL[n * 104 + ch * 8] = *(const int4*)&Wtb[n * FD + ch * 8];
        }
    }
    int row0 = blockIdx.x * 64;
    for (int j = 0; j < 4; j++) {
        int r = 16 * j + y;
        int n = row0 + r;
        float4 a = make_float4(0.f, 0.f, 0.f, 0.f);
        if (n < N) {
            if (n == HUB) {
                a = *(const float4*)&hubacc[4 * c];
            } else {
                a = agg_row(fh, rowptr, col, n, c);
                float dn = dinv[n];
                a.x *= dn; a.y *= dn; a.z *= dn; a.w *= dn;
            }
        }
        *(int2*)&As[r * 104 + 4 * c] = pack4(a.x, a.y, a.z, a.w);
    }
    __syncthreads();
    // MFMA dual GEMM (fragment layouts as verified in mfma_dual)
    int wv = t >> 6, lane = t & 63;
    int m = lane & 15, q = lane >> 4;
    int n0 = wv * 16;
    const f16x8* brA = (const f16x8*)&WtaL[(n0 + m) * 104 + q * 8];
    const f16x8* brB = (const f16x8*)&WtbL[(n0 + m) * 104 + q * 8];
    f16x8 Ba0 = brA[0], Ba1 = brA[4], Ba2 = brA[8];   // k +0,+32,+64
    f16x8 Bb0 = brB[0], Bb1 = brB[4], Bb2 = brB[8];
    float bva = ba[n0 + m];
    float bvb = bb[n0 + m];
    #pragma unroll
    for (int rt = 0; rt < 4; rt++) {
        const f16x8* ar = (const f16x8*)&As[(rt * 16 + m) * 104 + q * 8];
        f16x8 A0 = ar[0], A1 = ar[4], A2 = ar[8];
        f32x4 acca = {0.f, 0.f, 0.f, 0.f};
        f32x4 accb = {0.f, 0.f, 0.f, 0.f};
        acca = __builtin_amdgcn_mfma_f32_16x16x32_f16(A0, Ba0, acca, 0, 0, 0);
        acca = __builtin_amdgcn_mfma_f32_16x16x32_f16(A1, Ba1, acca, 0, 0, 0);
        acca = __builtin_amdgcn_mfma_f32_16x16x32_f16(A2, Ba2, acca, 0, 0, 0);
        accb = __builtin_amdgcn_mfma_f32_16x16x32_f16(A0, Bb0, accb, 0, 0, 0);
        accb = __builtin_amdgcn_mfma_f32_16x16x32_f16(A1, Bb1, accb, 0, 0, 0);
        accb = __builtin_amdgcn_mfma_f32_16x16x32_f16(A2, Bb2, accb, 0, 0, 0);
        #pragma unroll
        for (int rr = 0; rr < 4; rr++) {
            long row = row0 + rt * 16 + q * 4 + rr;
            if (row < N) {
                mu[row * FD + n0 + m] = acca[rr] + bva;
                ls[row * FD + n0 + m] = accb[rr] + bvb;
            }
        }
    }
}

// ---------------------------------------------------------------------------
// Launch. 9 dispatches (was 14). Numerics identical to previous version.
//   xh  = fp16(dinv*x)          -> mu slot (d_out)       [dead before mu write]
//   h1h = fp16 layer-1 output   -> ws (9.6 MB; mu_slot can't hold it: mu
//                                  write races layer-2 gathers)
//   a0 / a1h intermediates eliminated (live only in LDS inside fused kernels)
// ws: [counts N][hubacc1 96][hubacc2 96][perm E][rowptr N+1][col E][dinv N]
//     [W1h|Wta|Wtb 3x9216 h][h1h N*96 h]  ~= 17.3 MB
// ---------------------------------------------------------------------------
extern "C" void kernel_launch(void* const* d_in, const int* in_sizes, int n_in,
                              void* d_out, int out_size, void* d_ws, size_t ws_size,
                              hipStream_t stream) {
    const float* x   = (const float*)d_in[0];
    const float* W1  = (const float*)d_in[1];
    const float* b1  = (const float*)d_in[2];
    const float* W2a = (const float*)d_in[3];
    const float* b2a = (const float*)d_in[4];
    const float* W2b = (const float*)d_in[5];
    const float* b2b = (const float*)d_in[6];
    const int*   ei  = (const int*)d_in[7];

    const int N   = in_sizes[0] / FD;
    const int E   = in_sizes[7] / 2;
    const int HUB = N - 1;
    const int* src = ei;
    const int* dst = ei + E;
    const int NB  = (N + 1023) / 1024;

    int* counts    = (int*)d_ws;                 // N
    float* hubacc1 = (float*)(counts + N);       // 96
    float* hubacc2 = hubacc1 + FD;               // 96
    int* perm      = (int*)(hubacc2 + FD);       // E
    int* rowptr    = perm + E;                   // N+1
    int* col       = rowptr + (N + 1);           // E
    float* dinv    = (float*)(col + E);          // N
    uintptr_t p = (uintptr_t)(dinv + N);
    p = (p + 15) & ~(uintptr_t)15;
    __half* W1h = (__half*)p;                    // FD*FD
    __half* Wta = W1h + FD * FD;                 // FD*FD
    __half* Wtb = Wta + FD * FD;                 // FD*FD
    __half* h1h = Wtb + FD * FD;                 // N*FD halves (16B-aligned)

    float* mu_slot = (float*)d_out;
    float* ls_slot = (float*)d_out + (size_t)N * FD;
    int2* xh = (int2*)mu_slot;                   // 9.6 MB, dead before mu write

    // zero counts + both hub accumulators (contiguous)
    hipMemsetAsync(counts, 0, ((size_t)N + 2 * FD) * sizeof(int), stream);

    deg_kernel <<<dim3((E + 255) / 256), dim3(256), 0, stream>>>(dst, E, HUB,
                                                                 counts, perm);
    scan_kernel<<<dim3(NB), dim3(1024), 0, stream>>>(counts, N, rowptr, dinv);

    int gfill = (E + 255) / 256;
    int gconv = (N * 24 + 255) / 256;
    int gwt   = (FD * FD + 255) / 256;
    prep_kernel<<<dim3(gfill + gconv + gwt), dim3(256), 0, stream>>>(
        src, dst, perm, rowptr, E, x, dinv, N, W1, W2a, W2b,
        col, xh, W1h, Wta, Wtb, gfill, gconv);

    dim3 hubB(24, 8);
    dim3 aggB(24, 16);
    int  gemmG = (N + 63) / 64;

    // layer 1
    hub_kernel<<<dim3(256), hubB, 0, stream>>>(xh, dinv, rowptr, col, HUB, hubacc1);
    agg_gemm1 <<<dim3(gemmG), aggB, 0, stream>>>(xh, dinv, rowptr, col, W1h, b1,
                                                 hubacc1, N, HUB, (int2*)h1h);
    // layer 2
    hub_kernel<<<dim3(256), hubB, 0, stream>>>((const int2*)h1h, dinv, rowptr, col,
                                               HUB, hubacc2);
    agg_gemm2 <<<dim3(gemmG), aggB, 0, stream>>>((const int2*)h1h, dinv, rowptr, col,
                                                 Wta, Wtb, b2a, b2b, hubacc2,
                                                 N, HUB, mu_slot, ls_slot);
}

// Round 2
// 315.723 us; speedup vs baseline: 1.0576x; 1.0576x over previous
//
#include <hip/hip_runtime.h>
#include <hip/hip_fp16.h>

#define FD 96   // feature dim

typedef _Float16 f16x8 __attribute__((ext_vector_type(8)));
typedef float f32x4 __attribute__((ext_vector_type(4)));

// ---- fp16 pack/unpack helpers ---------------------------------------------
__device__ inline float2 unpack2(int v) {
    __half2 h = *reinterpret_cast<__half2*>(&v);
    return __half22float2(h);
}
__device__ inline int2 pack4(float a, float b, float c, float d) {
    __half2 lo = __floats2half2_rn(a, b);
    __half2 hi = __floats2half2_rn(c, d);
    int2 r;
    r.x = *reinterpret_cast<int*>(&lo);
    r.y = *reinterpret_cast<int*>(&hi);
    return r;
}
// load 4 fp16 (int2) from LDS -> float4
__device__ inline float4 lds_w4(const __half* Wl, int k, int c4) {
    int2 wv = *(const int2*)&Wl[k * FD + c4];
    float2 lo = unpack2(wv.x), hi = unpack2(wv.y);
    return make_float4(lo.x, lo.y, hi.x, hi.y);
}
// unpack 8 halves (int4) -> 8 floats
__device__ inline void unpack8(int4 r, float* f) {
    float2 p0 = unpack2(r.x), p1 = unpack2(r.y);
    float2 p2 = unpack2(r.z), p3 = unpack2(r.w);
    f[0] = p0.x; f[1] = p0.y; f[2] = p1.x; f[3] = p1.y;
    f[4] = p2.x; f[5] = p2.y; f[6] = p3.x; f[7] = p3.y;
}

// ---------------------------------------------------------------------------
// K1: degree histogram + per-edge rank capture (perm). Hub via ballot.
// ---------------------------------------------------------------------------
__global__ void deg_kernel(const int* __restrict__ dst, int E, int HUB,
                           int* __restrict__ counts, int* __restrict__ perm) {
    int e = blockIdx.x * 256 + threadIdx.x;
    int d = (e < E) ? dst[e] : -1;
    bool isHub = (d == HUB);
    unsigned long long m = __ballot(isHub);
    if (isHub) {
        int lane = threadIdx.x & 63;
        int leader = __ffsll((unsigned long long)m) - 1;
        int base = 0;
        if (lane == leader) base = atomicAdd(&counts[HUB], (int)__popcll(m));
        base = __shfl(base, leader);
        unsigned long long below = m & ((1ull << lane) - 1ull);
        perm[e] = base + (int)__popcll(below);
    } else if (d >= 0) {
        perm[e] = atomicAdd(&counts[d], 1);
    }
}

// ---------------------------------------------------------------------------
// K2: single-kernel scan. Block b brute-force sums counts[0..b*1024), then
// scans its own 1024-chunk. Emits rowptr[0..N] and dinv (fused).
// ---------------------------------------------------------------------------
__global__ __launch_bounds__(1024)
void scan_kernel(const int* __restrict__ counts, int N,
                 int* __restrict__ rowptr, float* __restrict__ dinv) {
    int t = threadIdx.x, lane = t & 63, wv = t >> 6;
    int base = blockIdx.x * 1024;
    int pre = 0;
    for (int idx = t; idx < base; idx += 1024) pre += counts[idx];
    #pragma unroll
    for (int off = 32; off; off >>= 1) pre += __shfl_down(pre, off);
    __shared__ int wsA[16];
    __shared__ int preS;
    if (lane == 0) wsA[wv] = pre;
    __syncthreads();
    if (t == 0) {
        int s = 0;
        #pragma unroll
        for (int k = 0; k < 16; k++) s += wsA[k];
        preS = s;
    }
    __syncthreads();
    int blockpre = preS;
    int i = base + t;
    int v = (i < N) ? counts[i] : 0;
    int x = v;
    #pragma unroll
    for (int off = 1; off < 64; off <<= 1) {
        int u = __shfl_up(x, off);
        if (lane >= off) x += u;
    }
    __shared__ int wsum[16];
    if (lane == 63) wsum[wv] = x;
    __syncthreads();
    if (wv == 0 && lane < 16) {
        int w = wsum[lane];
        #pragma unroll
        for (int off = 1; off < 16; off <<= 1) {
            int u = __shfl_up(w, off);
            if (lane >= off) w += u;
        }
        wsum[lane] = w;
    }
    __syncthreads();
    int waveoff = (wv == 0) ? 0 : wsum[wv - 1];
    if (i <= N) rowptr[i] = blockpre + waveoff + x - v;
    if (i < N) {
        float d = (float)v;
        dinv[i] = (d > 0.f) ? rsqrtf(fmaxf(d, 1.f)) : 0.f;
    }
}

// ---------------------------------------------------------------------------
// K3: prep — fused {CSR col fill} + {xh = fp16(dinv*x)} + {Wt convert}.
// ---------------------------------------------------------------------------
__global__ __launch_bounds__(256)
void prep_kernel(const int* __restrict__ src, const int* __restrict__ dst,
                 const int* __restrict__ perm, const int* __restrict__ rowptr,
                 int E,
                 const float* __restrict__ x, const float* __restrict__ dinv,
                 int N,
                 const float* __restrict__ W2a, const float* __restrict__ W2b,
                 int* __restrict__ col, int2* __restrict__ xh,
                 __half* __restrict__ Wta, __half* __restrict__ Wtb,
                 int gfill, int gconv) {
    int b = blockIdx.x;
    if (b < gfill) {
        int e = b * 256 + threadIdx.x;
        if (e >= E) return;
        int d = dst[e];
        col[rowptr[d] + perm[e]] = src[e];
    } else if (b < gfill + gconv) {
        int i = (b - gfill) * 256 + threadIdx.x;
        if (i >= N * 24) return;
        int n = i / 24;
        float dn = dinv[n];
        float4 a = ((const float4*)x)[i];
        xh[i] = pack4(a.x * dn, a.y * dn, a.z * dn, a.w * dn);
    } else {
        int i = (b - gfill - gconv) * 256 + threadIdx.x;
        if (i >= FD * FD) return;
        int n = i / FD, k = i % FD;
        Wta[i] = __float2half(W2a[k * FD + n]);
        Wtb[i] = __float2half(W2b[k * FD + n]);
    }
}

// ---- shared 16B-per-lane aggregation body (c in 0..11, 8 halves/lane) -----
__device__ inline void agg_row16(const int4* __restrict__ fh4,
                                 const int* __restrict__ rowptr,
                                 const int* __restrict__ col,
                                 int n, int c, float* ax) {
    int beg = rowptr[n], end = rowptr[n + 1];
    #pragma unroll
    for (int k = 0; k < 8; k++) ax[k] = 0.f;
    int e = beg;
    for (; e + 8 <= end; e += 8) {
        int s0 = col[e + 0], s1 = col[e + 1], s2 = col[e + 2], s3 = col[e + 3];
        int s4 = col[e + 4], s5 = col[e + 5], s6 = col[e + 6], s7 = col[e + 7];
        int4 r0 = fh4[(long)s0 * 12 + c], r1 = fh4[(long)s1 * 12 + c];
        int4 r2 = fh4[(long)s2 * 12 + c], r3 = fh4[(long)s3 * 12 + c];
        int4 r4 = fh4[(long)s4 * 12 + c], r5 = fh4[(long)s5 * 12 + c];
        int4 r6 = fh4[(long)s6 * 12 + c], r7 = fh4[(long)s7 * 12 + c];
        float f0[8], f1[8], f2[8], f3[8], f4[8], f5[8], f6[8], f7[8];
        unpack8(r0, f0); unpack8(r1, f1); unpack8(r2, f2); unpack8(r3, f3);
        unpack8(r4, f4); unpack8(r5, f5); unpack8(r6, f6); unpack8(r7, f7);
        #pragma unroll
        for (int k = 0; k < 8; k++)
            ax[k] += (f0[k] + f1[k]) + (f2[k] + f3[k]) +
                     (f4[k] + f5[k]) + (f6[k] + f7[k]);
    }
    for (; e < end; e++) {
        int s = col[e];
        int4 r = fh4[(long)s * 12 + c];
        float f[8];
        unpack8(r, f);
        #pragma unroll
        for (int k = 0; k < 8; k++) ax[k] += f[k];
    }
}

// ---------------------------------------------------------------------------
// K5: pull aggregation (fp32 out, layer 1). Block (12,32): 32 nodes/block,
// lane handles 16B (8 features) per edge -> half the gather instructions of
// the 24x8B layout. Addition order per feature identical to before.
// ---------------------------------------------------------------------------
__global__ __launch_bounds__(384)
void pull_kernel(const int4* __restrict__ fh4, const float* __restrict__ dinv,
                 const int* __restrict__ rowptr, const int* __restrict__ col,
                 int N, int HUB, float* __restrict__ out) {
    int c = threadIdx.x;                       // 0..11
    int n = blockIdx.x * 32 + threadIdx.y;
    if (n >= N) return;
    float4* out4 = (float4*)(out + (long)n * FD + c * 8);
    if (n == HUB) {
        out4[0] = make_float4(0.f, 0.f, 0.f, 0.f);
        out4[1] = make_float4(0.f, 0.f, 0.f, 0.f);
        return;
    }
    float ax[8];
    agg_row16(fh4, rowptr, col, n, c, ax);
    float dn = dinv[n];
    out4[0] = make_float4(ax[0] * dn, ax[1] * dn, ax[2] * dn, ax[3] * dn);
    out4[1] = make_float4(ax[4] * dn, ax[5] * dn, ax[6] * dn, ax[7] * dn);
}

// ---------------------------------------------------------------------------
// K5b: pull16 — same aggregation, fp16 packed output (feeds MFMA dual GEMM).
// ---------------------------------------------------------------------------
__global__ __launch_bounds__(384)
void pull16_kernel(const int4* __restrict__ fh4, const float* __restrict__ dinv,
                   const int* __restrict__ rowptr, const int* __restrict__ col,
                   int N, int HUB, int4* __restrict__ out16) {
    int c = threadIdx.x;                       // 0..11
    int n = blockIdx.x * 32 + threadIdx.y;
    if (n >= N) return;
    int4* ob = out16 + (long)n * 12 + c;
    if (n == HUB) { *ob = make_int4(0, 0, 0, 0); return; }
    float ax[8];
    agg_row16(fh4, rowptr, col, n, c, ax);
    float dn = dinv[n];
    int2 lo = pack4(ax[0] * dn, ax[1] * dn, ax[2] * dn, ax[3] * dn);
    int2 hi = pack4(ax[4] * dn, ax[5] * dn, ax[6] * dn, ax[7] * dn);
    *ob = make_int4(lo.x, lo.y, hi.x, hi.y);
}

// ---------------------------------------------------------------------------
// K6: hub row aggregation: dest[0..95] += dinv[HUB]*sum fh[s] (dest fp32,
// pre-zeroed). 256 blocks x 8 streams, LDS reduce, 96 atomics/block.
// ---------------------------------------------------------------------------
__global__ __launch_bounds__(192)
void hub_kernel(const int2* __restrict__ fh, const float* __restrict__ dinv,
                const int* __restrict__ rowptr, const int* __restrict__ col,
                int HUB, float* __restrict__ dest) {
    int c = threadIdx.x;   // 0..23
    int y = threadIdx.y;   // 0..7
    int beg = rowptr[HUB], end = rowptr[HUB + 1];
    int deg = end - beg;
    int nstr = gridDim.x * 8;
    int sid  = blockIdx.x * 8 + y;
    int chunk = (deg + nstr - 1) / nstr;
    int e  = beg + sid * chunk;
    int e1 = min(e + chunk, end);
    float ax = 0.f, ay = 0.f, az = 0.f, aw = 0.f;
    for (; e + 4 <= e1; e += 4) {
        int s0 = col[e + 0], s1 = col[e + 1], s2 = col[e + 2], s3 = col[e + 3];
        int2 r0 = fh[(long)s0 * 24 + c], r1 = fh[(long)s1 * 24 + c];
        int2 r2 = fh[(long)s2 * 24 + c], r3 = fh[(long)s3 * 24 + c];
        float2 l0 = unpack2(r0.x), h0 = unpack2(r0.y);
        float2 l1 = unpack2(r1.x), h1_ = unpack2(r1.y);
        float2 l2 = unpack2(r2.x), h2 = unpack2(r2.y);
        float2 l3 = unpack2(r3.x), h3 = unpack2(r3.y);
        ax += (l0.x + l1.x) + (l2.x + l3.x);
        ay += (l0.y + l1.y) + (l2.y + l3.y);
        az += (h0.x + h1_.x) + (h2.x + h3.x);
        aw += (h0.y + h1_.y) + (h2.y + h3.y);
    }
    for (; e < e1; e++) {
        int s = col[e];
        int2 r = fh[(long)s * 24 + c];
        float2 lo = unpack2(r.x), hi = unpack2(r.y);
        ax += lo.x; ay += lo.y; az += hi.x; aw += hi.y;
    }
    __shared__ float4 red[8][24];
    red[y][c] = make_float4(ax, ay, az, aw);
    __syncthreads();
    if (y == 0) {
        float4 t = red[0][c];
        #pragma unroll
        for (int k = 1; k < 8; k++) {
            float4 u = red[k][c];
            t.x += u.x; t.y += u.y; t.z += u.z; t.w += u.w;
        }
        float dh = dinv[HUB];
        float* o = dest + 4 * c;
        unsafeAtomicAdd(o + 0, t.x * dh);
        unsafeAtomicAdd(o + 1, t.y * dh);
        unsafeAtomicAdd(o + 2, t.z * dh);
        unsafeAtomicAdd(o + 3, t.w * dh);
    }
}

// ---------------------------------------------------------------------------
// K6b: pack_hub — a1h hub row = fp16(hubacc).  1 block x 24 threads.
// ---------------------------------------------------------------------------
__global__ void pack_hub(const float* __restrict__ hubacc, int HUB,
                         int2* __restrict__ a1h16) {
    int c = threadIdx.x;   // 0..23
    if (c < 24)
        a1h16[(long)HUB * 24 + c] = pack4(hubacc[4 * c + 0], hubacc[4 * c + 1],
                                          hubacc[4 * c + 2], hubacc[4 * c + 3]);
}

// ---------------------------------------------------------------------------
// K7: gemm96_h — h1h = fp16(dinv*relu(A@W1+b1)). W staged fp16 in LDS.
// ---------------------------------------------------------------------------
__global__ __launch_bounds__(192)
void gemm96_h(const float* __restrict__ A, const float* __restrict__ W,
              const float* __restrict__ bias, const float* __restrict__ dinv,
              int2* __restrict__ out16, int N) {
    __shared__ __half Wl[FD * FD];       // 18432 B
    __shared__ float As[64 * 100];       // 25600 B
    int t = threadIdx.y * 24 + threadIdx.x;
    {   // stage W fp32 -> fp16
        const float4* W4 = (const float4*)W;
        #pragma unroll 4
        for (int i = t; i < FD * 24; i += 192) {
            float4 w = W4[i];
            *(int2*)&Wl[i * 4] = pack4(w.x, w.y, w.z, w.w);
        }
    }
    int row0 = blockIdx.x * 64;
    int nrows = min(64, N - row0);
    {
        const float4* A4 = (const float4*)(A + (long)row0 * FD);
        for (int i = t; i < nrows * 24; i += 192) {
            int r = i / 24, g = i % 24;
            *(float4*)&As[r * 100 + g * 4] = A4[i];
        }
    }
    __syncthreads();
    int c = threadIdx.x, y = threadIdx.y;
    float acc[8][4];
    #pragma unroll
    for (int j = 0; j < 8; j++)
        #pragma unroll
        for (int i = 0; i < 4; i++) acc[j][i] = 0.f;
    for (int kk = 0; kk < FD; kk += 4) {
        float4 w0 = lds_w4(Wl, kk + 0, 4 * c);
        float4 w1 = lds_w4(Wl, kk + 1, 4 * c);
        float4 w2 = lds_w4(Wl, kk + 2, 4 * c);
        float4 w3 = lds_w4(Wl, kk + 3, 4 * c);
        #pragma unroll
        for (int j = 0; j < 8; j++) {
            float4 a = *(const float4*)&As[(y + 8 * j) * 100 + kk];
            acc[j][0] = fmaf(a.x, w0.x, fmaf(a.y, w1.x, fmaf(a.z, w2.x, fmaf(a.w, w3.x, acc[j][0]))));
            acc[j][1] = fmaf(a.x, w0.y, fmaf(a.y, w1.y, fmaf(a.z, w2.y, fmaf(a.w, w3.y, acc[j][1]))));
            acc[j][2] = fmaf(a.x, w0.z, fmaf(a.y, w1.z, fmaf(a.z, w2.z, fmaf(a.w, w3.z, acc[j][2]))));
            acc[j][3] = fmaf(a.x, w0.w, fmaf(a.y, w1.w, fmaf(a.z, w2.w, fmaf(a.w, w3.w, acc[j][3]))));
        }
    }
    float4 b4 = *(const float4*)&bias[4 * c];
    #pragma unroll
    for (int j = 0; j < 8; j++) {
        int r = y + 8 * j;
        if (r < nrows) {
            float vx = fmaxf(acc[j][0] + b4.x, 0.f);
            float vy = fmaxf(acc[j][1] + b4.y, 0.f);
            float vz = fmaxf(acc[j][2] + b4.z, 0.f);
            float vw = fmaxf(acc[j][3] + b4.w, 0.f);
            float dr = dinv[row0 + r];
            out16[(long)(row0 + r) * 24 + c] = pack4(vx * dr, vy * dr, vz * dr, vw * dr);
        }
    }
}

// ---------------------------------------------------------------------------
// K8: mfma_dual — mu = A@Wa+ba, ls = A@Wb+bb via v_mfma_f32_16x16x32_f16.
// A = a1h fp16 [padded >= N+64 rows][96]. Wta/Wtb = fp16 TRANSPOSED.
// ---------------------------------------------------------------------------
__global__ __launch_bounds__(256)
void mfma_dual(const __half* __restrict__ a1h,
               const __half* __restrict__ Wta, const __half* __restrict__ Wtb,
               const float* __restrict__ ba, const float* __restrict__ bb,
               float* __restrict__ mu, float* __restrict__ ls, int N) {
    __shared__ __half WtaL[FD * FD];     // 18432 B
    __shared__ __half WtbL[FD * FD];     // 18432 B
    int t = threadIdx.x;
    {
        const int4* sa = (const int4*)Wta;
        const int4* sb = (const int4*)Wtb;
        int4* da = (int4*)WtaL;
        int4* db = (int4*)WtbL;
        #pragma unroll
        for (int i = t; i < FD * FD / 8; i += 256) { da[i] = sa[i]; db[i] = sb[i]; }
    }
    __syncthreads();
    int wv = t >> 6, lane = t & 63;
    int m = lane & 15, q = lane >> 4;
    long row0 = (long)blockIdx.x * 64 + wv * 16;

    const f16x8* arow = (const f16x8*)&a1h[(row0 + m) * FD + q * 8];
    f16x8 A0 = arow[0];
    f16x8 A1 = arow[4];
    f16x8 A2 = arow[8];

    #pragma unroll
    for (int nt = 0; nt < 6; nt++) {
        int n0 = nt * 16;
        const f16x8* brA = (const f16x8*)&WtaL[(n0 + m) * FD + q * 8];
        const f16x8* brB = (const f16x8*)&WtbL[(n0 + m) * FD + q * 8];
        f32x4 acca = {0.f, 0.f, 0.f, 0.f};
        f32x4 accb = {0.f, 0.f, 0.f, 0.f};
        acca = __builtin_amdgcn_mfma_f32_16x16x32_f16(A0, brA[0], acca, 0, 0, 0);
        acca = __builtin_amdgcn_mfma_f32_16x16x32_f16(A1, brA[4], acca, 0, 0, 0);
        acca = __builtin_amdgcn_mfma_f32_16x16x32_f16(A2, brA[8], acca, 0, 0, 0);
        accb = __builtin_amdgcn_mfma_f32_16x16x32_f16(A0, brB[0], accb, 0, 0, 0);
        accb = __builtin_amdgcn_mfma_f32_16x16x32_f16(A1, brB[4], accb, 0, 0, 0);
        accb = __builtin_amdgcn_mfma_f32_16x16x32_f16(A2, brB[8], accb, 0, 0, 0);
        float bva = ba[n0 + m];
        float bvb = bb[n0 + m];
        #pragma unroll
        for (int r = 0; r < 4; r++) {
            long row = row0 + q * 4 + r;
            if (row < N) {
                mu[row * FD + n0 + m] = acca[r] + bva;
                ls[row * FD + n0 + m] = accb[r] + bvb;
            }
        }
    }
}

// ---------------------------------------------------------------------------
// Launch. 11 dispatches. Round-0 split structure (verified 305us) + fused
// scan/prep + 16B-lane pull kernels.
//   xh  = fp16(dinv*x)              -> mu slot, lower 9.6 MB
//   a0  = agg(xh)  (pull+hub)       -> ls slot (fp32)
//   h1h = fp16(dinv*relu(a0@W1+b1)) -> mu slot, upper 9.6 MB  (a0 dead)
//   a1h = fp16 agg(h1h)             -> ws (pull16 + hub->hubacc->pack)
//   mu,ls = MFMA dual-gemm(a1h)     -> d_out (xh,h1h,a0 all dead)
// ws: [counts N][hubacc 96][perm E][rowptr N+1][col E][dinv N]
//     [Wta][Wtb][a1h (N+64)x96 h]  ~= 17.5 MB
// ---------------------------------------------------------------------------
extern "C" void kernel_launch(void* const* d_in, const int* in_sizes, int n_in,
                              void* d_out, int out_size, void* d_ws, size_t ws_size,
                              hipStream_t stream) {
    const float* x   = (const float*)d_in[0];
    const float* W1  = (const float*)d_in[1];
    const float* b1  = (const float*)d_in[2];
    const float* W2a = (const float*)d_in[3];
    const float* b2a = (const float*)d_in[4];
    const float* W2b = (const float*)d_in[5];
    const float* b2b = (const float*)d_in[6];
    const int*   ei  = (const int*)d_in[7];

    const int N   = in_sizes[0] / FD;
    const int E   = in_sizes[7] / 2;
    const int HUB = N - 1;
    const int* src = ei;
    const int* dst = ei + E;
    const int NB  = (N + 1023) / 1024;

    int* counts   = (int*)d_ws;                 // N
    float* hubacc = (float*)(counts + N);       // 96
    int* perm     = (int*)(hubacc + FD);        // E
    int* rowptr   = perm + E;                   // N+1
    int* col      = rowptr + (N + 1);           // E
    float* dinv   = (float*)(col + E);          // N
    uintptr_t p = (uintptr_t)(dinv + N);
    p = (p + 15) & ~(uintptr_t)15;
    __half* Wta = (__half*)p;                   // FD*FD
    __half* Wtb = Wta + FD * FD;                // FD*FD
    __half* a1h = Wtb + FD * FD;                // (N+64)*FD halves, 16B-aligned

    float* mu_slot = (float*)d_out;
    float* ls_slot = (float*)d_out + (size_t)N * FD;
    int2* xh  = (int2*)mu_slot;                      // 9.6 MB
    int2* h1h = (int2*)mu_slot + (size_t)N * 24;     // next 9.6 MB
    float* a0 = ls_slot;

    // zero counts + hubacc (contiguous)
    hipMemsetAsync(counts, 0, ((size_t)N + FD) * sizeof(int), stream);

    deg_kernel <<<dim3((E + 255) / 256), dim3(256), 0, stream>>>(dst, E, HUB,
                                                                 counts, perm);
    scan_kernel<<<dim3(NB), dim3(1024), 0, stream>>>(counts, N, rowptr, dinv);

    int gfill = (E + 255) / 256;
    int gconv = (N * 24 + 255) / 256;
    int gwt   = (FD * FD + 255) / 256;
    prep_kernel<<<dim3(gfill + gconv + gwt), dim3(256), 0, stream>>>(
        src, dst, perm, rowptr, E, x, dinv, N, W2a, W2b,
        col, xh, Wta, Wtb, gfill, gconv);

    dim3 pullB(12, 32);
    int  pullG = (N + 31) / 32;
    dim3 hubB(24, 8);
    int  hubG = 256;
    int  gemmG = (N + 63) / 64;
    dim3 gemmB(24, 8);

    // layer 1
    pull_kernel<<<dim3(pullG), pullB, 0, stream>>>((const int4*)xh, dinv, rowptr,
                                                   col, N, HUB, a0);
    hub_kernel <<<dim3(hubG),  hubB, 0, stream>>>(xh, dinv, rowptr, col, HUB,
                                                  a0 + (size_t)HUB * FD);
    gemm96_h   <<<dim3(gemmG), gemmB, 0, stream>>>(a0, W1, b1, dinv, h1h, N);

    // layer 2
    pull16_kernel<<<dim3(pullG), pullB, 0, stream>>>((const int4*)h1h, dinv, rowptr,
                                                     col, N, HUB, (int4*)a1h);
    hub_kernel   <<<dim3(hubG),  hubB, 0, stream>>>(h1h, dinv, rowptr, col, HUB,
                                                    hubacc);
    pack_hub     <<<dim3(1), dim3(24), 0, stream>>>(hubacc, HUB, (int2*)a1h);
    mfma_dual    <<<dim3(gemmG), dim3(256), 0, stream>>>(a1h, Wta, Wtb, b2a, b2b,
                                                         mu_slot, ls_slot, N);
}

// Round 4
// 264.954 us; speedup vs baseline: 1.2603x; 1.1916x over previous
//
#include <hip/hip_runtime.h>
#include <hip/hip_fp16.h>

#define FD 96        // feature dim
#define COL_CAP 2048 // LDS col staging capacity (16 rows, avg ~18 edges; only
                     // the block containing HUB (~50K edges) overflows)

typedef _Float16 f16x8 __attribute__((ext_vector_type(8)));
typedef float f32x4 __attribute__((ext_vector_type(4)));

// ---- fp16 pack/unpack helpers ---------------------------------------------
__device__ inline float2 unpack2(int v) {
    __half2 h = *reinterpret_cast<__half2*>(&v);
    return __half22float2(h);
}
__device__ inline int2 pack4(float a, float b, float c, float d) {
    __half2 lo = __floats2half2_rn(a, b);
    __half2 hi = __floats2half2_rn(c, d);
    int2 r;
    r.x = *reinterpret_cast<int*>(&lo);
    r.y = *reinterpret_cast<int*>(&hi);
    return r;
}
// pack 8 fp32 -> f16x8 with pack4 rounding (== pack_hub path)
__device__ inline f16x8 pack8h(const float* __restrict__ h) {
    int2 a = pack4(h[0], h[1], h[2], h[3]);
    int2 b = pack4(h[4], h[5], h[6], h[7]);
    int4 r = make_int4(a.x, a.y, b.x, b.y);
    return *reinterpret_cast<f16x8*>(&r);
}
// load 4 fp16 (int2) from LDS -> float4
__device__ inline float4 lds_w4(const __half* Wl, int k, int c4) {
    int2 wv = *(const int2*)&Wl[k * FD + c4];
    float2 lo = unpack2(wv.x), hi = unpack2(wv.y);
    return make_float4(lo.x, lo.y, hi.x, hi.y);
}

// ---- 24-lane 8-unroll aggregation (identical arithmetic order to the
// verified round-0 pull kernels). COLX(e) supplies the source index.
#define AGG24_BODY(COLX)                                                      \
    float ax = 0.f, ay = 0.f, az = 0.f, aw = 0.f;                             \
    int e = beg;                                                              \
    for (; e + 8 <= end; e += 8) {                                            \
        int s0 = COLX(e + 0), s1 = COLX(e + 1), s2 = COLX(e + 2), s3 = COLX(e + 3); \
        int s4 = COLX(e + 4), s5 = COLX(e + 5), s6 = COLX(e + 6), s7 = COLX(e + 7); \
        int2 r0 = fh[(long)s0 * 24 + c], r1 = fh[(long)s1 * 24 + c];          \
        int2 r2 = fh[(long)s2 * 24 + c], r3 = fh[(long)s3 * 24 + c];          \
        int2 r4 = fh[(long)s4 * 24 + c], r5 = fh[(long)s5 * 24 + c];          \
        int2 r6 = fh[(long)s6 * 24 + c], r7 = fh[(long)s7 * 24 + c];          \
        float2 l0 = unpack2(r0.x), h0 = unpack2(r0.y);                        \
        float2 l1 = unpack2(r1.x), h1_ = unpack2(r1.y);                       \
        float2 l2 = unpack2(r2.x), h2 = unpack2(r2.y);                        \
        float2 l3 = unpack2(r3.x), h3 = unpack2(r3.y);                        \
        float2 l4 = unpack2(r4.x), h4 = unpack2(r4.y);                        \
        float2 l5 = unpack2(r5.x), h5 = unpack2(r5.y);                        \
        float2 l6 = unpack2(r6.x), h6 = unpack2(r6.y);                        \
        float2 l7 = unpack2(r7.x), h7 = unpack2(r7.y);                        \
        ax += (l0.x + l1.x) + (l2.x + l3.x) + (l4.x + l5.x) + (l6.x + l7.x);  \
        ay += (l0.y + l1.y) + (l2.y + l3.y) + (l4.y + l5.y) + (l6.y + l7.y);  \
        az += (h0.x + h1_.x) + (h2.x + h3.x) + (h4.x + h5.x) + (h6.x + h7.x); \
        aw += (h0.y + h1_.y) + (h2.y + h3.y) + (h4.y + h5.y) + (h6.y + h7.y); \
    }                                                                         \
    for (; e < end; e++) {                                                    \
        int s = COLX(e);                                                      \
        int2 r = fh[(long)s * 24 + c];                                        \
        float2 lo = unpack2(r.x), hi = unpack2(r.y);                          \
        ax += lo.x; ay += lo.y; az += hi.x; aw += hi.y;                       \
    }

__device__ inline float4 agg24_glb(const int2* __restrict__ fh,
                                   const int* __restrict__ col,
                                   int beg, int end, int c) {
    #define COLG(E) col[E]
    AGG24_BODY(COLG)
    #undef COLG
    return make_float4(ax, ay, az, aw);
}
__device__ inline float4 agg24_lds(const int2* __restrict__ fh,
                                   const int* colS, int beg, int end, int c) {
    #define COLS(E) colS[E]
    AGG24_BODY(COLS)
    #undef COLS
    return make_float4(ax, ay, az, aw);
}

// ---------------------------------------------------------------------------
// K1: degree histogram + per-edge rank capture (perm). Hub via ballot.
// ---------------------------------------------------------------------------
__global__ void deg_kernel(const int* __restrict__ dst, int E, int HUB,
                           int* __restrict__ counts, int* __restrict__ perm) {
    int e = blockIdx.x * 256 + threadIdx.x;
    int d = (e < E) ? dst[e] : -1;
    bool isHub = (d == HUB);
    unsigned long long m = __ballot(isHub);
    if (isHub) {
        int lane = threadIdx.x & 63;
        int leader = __ffsll((unsigned long long)m) - 1;
        int base = 0;
        if (lane == leader) base = atomicAdd(&counts[HUB], (int)__popcll(m));
        base = __shfl(base, leader);
        unsigned long long below = m & ((1ull << lane) - 1ull);
        perm[e] = base + (int)__popcll(below);
    } else if (d >= 0) {
        perm[e] = atomicAdd(&counts[d], 1);
    }
}

// ---------------------------------------------------------------------------
// K2: single-kernel scan. Block b brute-force sums counts[0..b*1024), then
// scans its own 1024-chunk. Emits rowptr[0..N] and dinv (fused).
// ---------------------------------------------------------------------------
__global__ __launch_bounds__(1024)
void scan_kernel(const int* __restrict__ counts, int N,
                 int* __restrict__ rowptr, float* __restrict__ dinv) {
    int t = threadIdx.x, lane = t & 63, wv = t >> 6;
    int base = blockIdx.x * 1024;
    int pre = 0;
    for (int idx = t; idx < base; idx += 1024) pre += counts[idx];
    #pragma unroll
    for (int off = 32; off; off >>= 1) pre += __shfl_down(pre, off);
    __shared__ int wsA[16];
    __shared__ int preS;
    if (lane == 0) wsA[wv] = pre;
    __syncthreads();
    if (t == 0) {
        int s = 0;
        #pragma unroll
        for (int k = 0; k < 16; k++) s += wsA[k];
        preS = s;
    }
    __syncthreads();
    int blockpre = preS;
    int i = base + t;
    int v = (i < N) ? counts[i] : 0;
    int x = v;
    #pragma unroll
    for (int off = 1; off < 64; off <<= 1) {
        int u = __shfl_up(x, off);
        if (lane >= off) x += u;
    }
    __shared__ int wsum[16];
    if (lane == 63) wsum[wv] = x;
    __syncthreads();
    if (wv == 0 && lane < 16) {
        int w = wsum[lane];
        #pragma unroll
        for (int off = 1; off < 16; off <<= 1) {
            int u = __shfl_up(w, off);
            if (lane >= off) w += u;
        }
        wsum[lane] = w;
    }
    __syncthreads();
    int waveoff = (wv == 0) ? 0 : wsum[wv - 1];
    if (i <= N) rowptr[i] = blockpre + waveoff + x - v;
    if (i < N) {
        float d = (float)v;
        dinv[i] = (d > 0.f) ? rsqrtf(fmaxf(d, 1.f)) : 0.f;
    }
}

// ---------------------------------------------------------------------------
// K3: prep — fused {CSR col fill} + {xh = fp16(dinv*x)} + {Wt convert} +
// {zero a0 hub row} (hub atomics accumulate into it next kernel).
// ---------------------------------------------------------------------------
__global__ __launch_bounds__(256)
void prep_kernel(const int* __restrict__ src, const int* __restrict__ dst,
                 const int* __restrict__ perm, const int* __restrict__ rowptr,
                 int E,
                 const float* __restrict__ x, const float* __restrict__ dinv,
                 int N,
                 const float* __restrict__ W2a, const float* __restrict__ W2b,
                 int* __restrict__ col, int2* __restrict__ xh,
                 __half* __restrict__ Wta, __half* __restrict__ Wtb,
                 float* __restrict__ a0hub, int gfill, int gconv, int gwt) {
    int b = blockIdx.x;
    if (b < gfill) {
        int e = b * 256 + threadIdx.x;
        if (e >= E) return;
        int d = dst[e];
        col[rowptr[d] + perm[e]] = src[e];
    } else if (b < gfill + gconv) {
        int i = (b - gfill) * 256 + threadIdx.x;
        if (i >= N * 24) return;
        int n = i / 24;
        float dn = dinv[n];
        float4 a = ((const float4*)x)[i];
        xh[i] = pack4(a.x * dn, a.y * dn, a.z * dn, a.w * dn);
    } else if (b < gfill + gconv + gwt) {
        int i = (b - gfill - gconv) * 256 + threadIdx.x;
        if (i >= FD * FD) return;
        int n = i / FD, k = i % FD;
        Wta[i] = __float2half(W2a[k * FD + n]);
        Wtb[i] = __float2half(W2b[k * FD + n]);
    } else {
        int i = threadIdx.x;
        if (i < FD) a0hub[i] = 0.f;
    }
}

// ---------------------------------------------------------------------------
// Merged pull+hub kernels. Grid = pullG + 128.
//   blocks [0, pullG): pull — 16 rows/block, block's contiguous col span
//     staged into LDS (coalesced once; inner loop reads cols via LDS
//     broadcast instead of 24x-redundant global loads). The block whose span
//     exceeds COL_CAP (the one containing HUB) falls back to global cols.
//   blocks [pullG, pullG+128): hub — 2048 streams (same chunking as the old
//     256x8 hub kernel -> identical per-stream partials), LDS reduce,
//     atomicAdd into hubdest.
// ---------------------------------------------------------------------------
__global__ __launch_bounds__(384)
void pull_hub32(const int2* __restrict__ fh, const float* __restrict__ dinv,
                const int* __restrict__ rowptr, const int* __restrict__ col,
                int N, int HUB, int pullG,
                float* __restrict__ out, float* __restrict__ hubdest) {
    __shared__ int colS[COL_CAP];
    __shared__ float4 red[16][24];
    int t = threadIdx.x;
    int c = t % 24, y = t / 24;
    if ((int)blockIdx.x < pullG) {
        int n0 = blockIdx.x * 16;
        int nend = min(n0 + 16, N);
        int beg0 = rowptr[n0];
        int span = rowptr[nend] - beg0;
        bool staged = (span <= COL_CAP);
        if (staged) {
            for (int i = t; i < span; i += 384) colS[i] = col[beg0 + i];
            __syncthreads();
        }
        int n = n0 + y;
        if (n < N && n != HUB) {
            int beg = rowptr[n], end = rowptr[n + 1];
            float4 a = staged ? agg24_lds(fh, colS, beg - beg0, end - beg0, c)
                              : agg24_glb(fh, col, beg, end, c);
            float dn = dinv[n];
            ((float4*)out)[(long)n * 24 + c] =
                make_float4(a.x * dn, a.y * dn, a.z * dn, a.w * dn);
        }
    } else {
        int beg = rowptr[HUB], end = rowptr[HUB + 1];
        int deg = end - beg;
        int nstr = 128 * 16;
        int sid = ((int)blockIdx.x - pullG) * 16 + y;
        int chunk = (deg + nstr - 1) / nstr;
        int e = beg + sid * chunk;
        int e1 = min(e + chunk, end);
        float ax = 0.f, ay = 0.f, az = 0.f, aw = 0.f;
        for (; e + 4 <= e1; e += 4) {
            int s0 = col[e + 0], s1 = col[e + 1], s2 = col[e + 2], s3 = col[e + 3];
            int2 r0 = fh[(long)s0 * 24 + c], r1 = fh[(long)s1 * 24 + c];
            int2 r2 = fh[(long)s2 * 24 + c], r3 = fh[(long)s3 * 24 + c];
            float2 l0 = unpack2(r0.x), h0 = unpack2(r0.y);
            float2 l1 = unpack2(r1.x), h1_ = unpack2(r1.y);
            float2 l2 = unpack2(r2.x), h2 = unpack2(r2.y);
            float2 l3 = unpack2(r3.x), h3 = unpack2(r3.y);
            ax += (l0.x + l1.x) + (l2.x + l3.x);
            ay += (l0.y + l1.y) + (l2.y + l3.y);
            az += (h0.x + h1_.x) + (h2.x + h3.x);
            aw += (h0.y + h1_.y) + (h2.y + h3.y);
        }
        for (; e < e1; e++) {
            int s = col[e];
            int2 r = fh[(long)s * 24 + c];
            float2 lo = unpack2(r.x), hi = unpack2(r.y);
            ax += lo.x; ay += lo.y; az += hi.x; aw += hi.y;
        }
        red[y][c] = make_float4(ax, ay, az, aw);
        __syncthreads();
        if (y == 0) {
            float4 tt = red[0][c];
            #pragma unroll
            for (int k = 1; k < 16; k++) {
                float4 u = red[k][c];
                tt.x += u.x; tt.y += u.y; tt.z += u.z; tt.w += u.w;
            }
            float dh = dinv[HUB];
            float* o = hubdest + 4 * c;
            unsafeAtomicAdd(o + 0, tt.x * dh);
            unsafeAtomicAdd(o + 1, tt.y * dh);
            unsafeAtomicAdd(o + 2, tt.z * dh);
            unsafeAtomicAdd(o + 3, tt.w * dh);
        }
    }
}

__global__ __launch_bounds__(384)
void pull_hub16(const int2* __restrict__ fh, const float* __restrict__ dinv,
                const int* __restrict__ rowptr, const int* __restrict__ col,
                int N, int HUB, int pullG,
                int2* __restrict__ out16, float* __restrict__ hubdest) {
    __shared__ int colS[COL_CAP];
    __shared__ float4 red[16][24];
    int t = threadIdx.x;
    int c = t % 24, y = t / 24;
    if ((int)blockIdx.x < pullG) {
        int n0 = blockIdx.x * 16;
        int nend = min(n0 + 16, N);
        int beg0 = rowptr[n0];
        int span = rowptr[nend] - beg0;
        bool staged = (span <= COL_CAP);
        if (staged) {
            for (int i = t; i < span; i += 384) colS[i] = col[beg0 + i];
            __syncthreads();
        }
        int n = n0 + y;
        if (n < N && n != HUB) {
            int beg = rowptr[n], end = rowptr[n + 1];
            float4 a = staged ? agg24_lds(fh, colS, beg - beg0, end - beg0, c)
                              : agg24_glb(fh, col, beg, end, c);
            float dn = dinv[n];
            out16[(long)n * 24 + c] =
                pack4(a.x * dn, a.y * dn, a.z * dn, a.w * dn);
        }
    } else {
        int beg = rowptr[HUB], end = rowptr[HUB + 1];
        int deg = end - beg;
        int nstr = 128 * 16;
        int sid = ((int)blockIdx.x - pullG) * 16 + y;
        int chunk = (deg + nstr - 1) / nstr;
        int e = beg + sid * chunk;
        int e1 = min(e + chunk, end);
        float ax = 0.f, ay = 0.f, az = 0.f, aw = 0.f;
        for (; e + 4 <= e1; e += 4) {
            int s0 = col[e + 0], s1 = col[e + 1], s2 = col[e + 2], s3 = col[e + 3];
            int2 r0 = fh[(long)s0 * 24 + c], r1 = fh[(long)s1 * 24 + c];
            int2 r2 = fh[(long)s2 * 24 + c], r3 = fh[(long)s3 * 24 + c];
            float2 l0 = unpack2(r0.x), h0 = unpack2(r0.y);
            float2 l1 = unpack2(r1.x), h1_ = unpack2(r1.y);
            float2 l2 = unpack2(r2.x), h2 = unpack2(r2.y);
            float2 l3 = unpack2(r3.x), h3 = unpack2(r3.y);
            ax += (l0.x + l1.x) + (l2.x + l3.x);
            ay += (l0.y + l1.y) + (l2.y + l3.y);
            az += (h0.x + h1_.x) + (h2.x + h3.x);
            aw += (h0.y + h1_.y) + (h2.y + h3.y);
        }
        for (; e < e1; e++) {
            int s = col[e];
            int2 r = fh[(long)s * 24 + c];
            float2 lo = unpack2(r.x), hi = unpack2(r.y);
            ax += lo.x; ay += lo.y; az += hi.x; aw += hi.y;
        }
        red[y][c] = make_float4(ax, ay, az, aw);
        __syncthreads();
        if (y == 0) {
            float4 tt = red[0][c];
            #pragma unroll
            for (int k = 1; k < 16; k++) {
                float4 u = red[k][c];
                tt.x += u.x; tt.y += u.y; tt.z += u.z; tt.w += u.w;
            }
            float dh = dinv[HUB];
            float* o = hubdest + 4 * c;
            unsafeAtomicAdd(o + 0, tt.x * dh);
            unsafeAtomicAdd(o + 1, tt.y * dh);
            unsafeAtomicAdd(o + 2, tt.z * dh);
            unsafeAtomicAdd(o + 3, tt.w * dh);
        }
    }
}

// ---------------------------------------------------------------------------
// K7: gemm96_h — h1h = fp16(dinv*relu(A@W1+b1)). W staged fp16 in LDS.
// ---------------------------------------------------------------------------
__global__ __launch_bounds__(192)
void gemm96_h(const float* __restrict__ A, const float* __restrict__ W,
              const float* __restrict__ bias, const float* __restrict__ dinv,
              int2* __restrict__ out16, int N) {
    __shared__ __half Wl[FD * FD];       // 18432 B
    __shared__ float As[64 * 100];       // 25600 B
    int t = threadIdx.y * 24 + threadIdx.x;
    {   // stage W fp32 -> fp16
        const float4* W4 = (const float4*)W;
        #pragma unroll 4
        for (int i = t; i < FD * 24; i += 192) {
            float4 w = W4[i];
            *(int2*)&Wl[i * 4] = pack4(w.x, w.y, w.z, w.w);
        }
    }
    int row0 = blockIdx.x * 64;
    int nrows = min(64, N - row0);
    {
        const float4* A4 = (const float4*)(A + (long)row0 * FD);
        for (int i = t; i < nrows * 24; i += 192) {
            int r = i / 24, g = i % 24;
            *(float4*)&As[r * 100 + g * 4] = A4[i];
        }
    }
    __syncthreads();
    int c = threadIdx.x, y = threadIdx.y;
    float acc[8][4];
    #pragma unroll
    for (int j = 0; j < 8; j++)
        #pragma unroll
        for (int i = 0; i < 4; i++) acc[j][i] = 0.f;
    for (int kk = 0; kk < FD; kk += 4) {
        float4 w0 = lds_w4(Wl, kk + 0, 4 * c);
        float4 w1 = lds_w4(Wl, kk + 1, 4 * c);
        float4 w2 = lds_w4(Wl, kk + 2, 4 * c);
        float4 w3 = lds_w4(Wl, kk + 3, 4 * c);
        #pragma unroll
        for (int j = 0; j < 8; j++) {
            float4 a = *(const float4*)&As[(y + 8 * j) * 100 + kk];
            acc[j][0] = fmaf(a.x, w0.x, fmaf(a.y, w1.x, fmaf(a.z, w2.x, fmaf(a.w, w3.x, acc[j][0]))));
            acc[j][1] = fmaf(a.x, w0.y, fmaf(a.y, w1.y, fmaf(a.z, w2.y, fmaf(a.w, w3.y, acc[j][1]))));
            acc[j][2] = fmaf(a.x, w0.z, fmaf(a.y, w1.z, fmaf(a.z, w2.z, fmaf(a.w, w3.z, acc[j][2]))));
            acc[j][3] = fmaf(a.x, w0.w, fmaf(a.y, w1.w, fmaf(a.z, w2.w, fmaf(a.w, w3.w, acc[j][3]))));
        }
    }
    float4 b4 = *(const float4*)&bias[4 * c];
    #pragma unroll
    for (int j = 0; j < 8; j++) {
        int r = y + 8 * j;
        if (r < nrows) {
            float vx = fmaxf(acc[j][0] + b4.x, 0.f);
            float vy = fmaxf(acc[j][1] + b4.y, 0.f);
            float vz = fmaxf(acc[j][2] + b4.z, 0.f);
            float vw = fmaxf(acc[j][3] + b4.w, 0.f);
            float dr = dinv[row0 + r];
            out16[(long)(row0 + r) * 24 + c] = pack4(vx * dr, vy * dr, vz * dr, vw * dr);
        }
    }
}

// ---------------------------------------------------------------------------
// K8: mfma_dual — mu = A@Wa+ba, ls = A@Wb+bb via v_mfma_f32_16x16x32_f16.
// Lanes whose row == HUB synthesize A-fragments from hubacc (fp32) with
// pack4 rounding — replaces the old pack_hub dispatch bit-for-bit.
// ---------------------------------------------------------------------------
__global__ __launch_bounds__(256)
void mfma_dual(const __half* __restrict__ a1h, const float* __restrict__ hubacc,
               const __half* __restrict__ Wta, const __half* __restrict__ Wtb,
               const float* __restrict__ ba, const float* __restrict__ bb,
               float* __restrict__ mu, float* __restrict__ ls, int N, int HUB) {
    __shared__ __half WtaL[FD * FD];     // 18432 B
    __shared__ __half WtbL[FD * FD];     // 18432 B
    int t = threadIdx.x;
    {
        const int4* sa = (const int4*)Wta;
        const int4* sb = (const int4*)Wtb;
        int4* da = (int4*)WtaL;
        int4* db = (int4*)WtbL;
        #pragma unroll
        for (int i = t; i < FD * FD / 8; i += 256) { da[i] = sa[i]; db[i] = sb[i]; }
    }
    __syncthreads();
    int wv = t >> 6, lane = t & 63;
    int m = lane & 15, q = lane >> 4;
    long row0 = (long)blockIdx.x * 64 + wv * 16;

    const f16x8* arow = (const f16x8*)&a1h[(row0 + m) * FD + q * 8];
    f16x8 A0 = arow[0];
    f16x8 A1 = arow[4];
    f16x8 A2 = arow[8];
    if (row0 + m == HUB) {   // hub row: a1h[HUB] never written; build from fp32
        A0 = pack8h(hubacc + q * 8);
        A1 = pack8h(hubacc + 32 + q * 8);
        A2 = pack8h(hubacc + 64 + q * 8);
    }

    #pragma unroll
    for (int nt = 0; nt < 6; nt++) {
        int n0 = nt * 16;
        const f16x8* brA = (const f16x8*)&WtaL[(n0 + m) * FD + q * 8];
        const f16x8* brB = (const f16x8*)&WtbL[(n0 + m) * FD + q * 8];
        f32x4 acca = {0.f, 0.f, 0.f, 0.f};
        f32x4 accb = {0.f, 0.f, 0.f, 0.f};
        acca = __builtin_amdgcn_mfma_f32_16x16x32_f16(A0, brA[0], acca, 0, 0, 0);
        acca = __builtin_amdgcn_mfma_f32_16x16x32_f16(A1, brA[4], acca, 0, 0, 0);
        acca = __builtin_amdgcn_mfma_f32_16x16x32_f16(A2, brA[8], acca, 0, 0, 0);
        accb = __builtin_amdgcn_mfma_f32_16x16x32_f16(A0, brB[0], accb, 0, 0, 0);
        accb = __builtin_amdgcn_mfma_f32_16x16x32_f16(A1, brB[4], accb, 0, 0, 0);
        accb = __builtin_amdgcn_mfma_f32_16x16x32_f16(A2, brB[8], accb, 0, 0, 0);
        float bva = ba[n0 + m];
        float bvb = bb[n0 + m];
        #pragma unroll
        for (int r = 0; r < 4; r++) {
            long row = row0 + q * 4 + r;
            if (row < N) {
                mu[row * FD + n0 + m] = acca[r] + bva;
                ls[row * FD + n0 + m] = accb[r] + bvb;
            }
        }
    }
}

// ---------------------------------------------------------------------------
// Launch. 8 dispatches (was 11): memset, deg, scan, prep, pull_hub32,
// gemm96_h, pull_hub16, mfma_dual.
//   xh  = fp16(dinv*x)              -> mu slot, lower 9.6 MB
//   a0  = agg(xh)                   -> ls slot (fp32; hub row pre-zeroed by
//                                      prep, filled by merged hub atomics)
//   h1h = fp16(dinv*relu(a0@W1+b1)) -> mu slot, upper 9.6 MB  (a0 dead)
//   a1h = fp16 agg(h1h)             -> ws (hub row via hubacc in mfma_dual)
//   mu,ls = MFMA dual-gemm(a1h)     -> d_out (xh,h1h,a0 all dead)
// ws: [counts N][hubacc 96][perm E][rowptr N+1][col E][dinv N]
//     [Wta][Wtb][a1h (N+64)x96 h]  ~= 17.5 MB
// ---------------------------------------------------------------------------
extern "C" void kernel_launch(void* const* d_in, const int* in_sizes, int n_in,
                              void* d_out, int out_size, void* d_ws, size_t ws_size,
                              hipStream_t stream) {
    const float* x   = (const float*)d_in[0];
    const float* W1  = (const float*)d_in[1];
    const float* b1  = (const float*)d_in[2];
    const float* W2a = (const float*)d_in[3];
    const float* b2a = (const float*)d_in[4];
    const float* W2b = (const float*)d_in[5];
    const float* b2b = (const float*)d_in[6];
    const int*   ei  = (const int*)d_in[7];

    const int N   = in_sizes[0] / FD;
    const int E   = in_sizes[7] / 2;
    const int HUB = N - 1;
    const int* src = ei;
    const int* dst = ei + E;
    const int NB  = (N + 1023) / 1024;

    int* counts   = (int*)d_ws;                 // N
    float* hubacc = (float*)(counts + N);       // 96
    int* perm     = (int*)(hubacc + FD);        // E
    int* rowptr   = perm + E;                   // N+1
    int* col      = rowptr + (N + 1);           // E
    float* dinv   = (float*)(col + E);          // N
    uintptr_t p = (uintptr_t)(dinv + N);
    p = (p + 15) & ~(uintptr_t)15;
    __half* Wta = (__half*)p;                   // FD*FD
    __half* Wtb = Wta + FD * FD;                // FD*FD
    __half* a1h = Wtb + FD * FD;                // (N+64)*FD halves, 16B-aligned

    float* mu_slot = (float*)d_out;
    float* ls_slot = (float*)d_out + (size_t)N * FD;
    int2* xh  = (int2*)mu_slot;                      // 9.6 MB
    int2* h1h = (int2*)mu_slot + (size_t)N * 24;     // next 9.6 MB
    float* a0 = ls_slot;

    // zero counts + hubacc (contiguous)
    (void)hipMemsetAsync(counts, 0, ((size_t)N + FD) * sizeof(int), stream);

    deg_kernel <<<dim3((E + 255) / 256), dim3(256), 0, stream>>>(dst, E, HUB,
                                                                 counts, perm);
    scan_kernel<<<dim3(NB), dim3(1024), 0, stream>>>(counts, N, rowptr, dinv);

    int gfill = (E + 255) / 256;
    int gconv = (N * 24 + 255) / 256;
    int gwt   = (FD * FD + 255) / 256;
    prep_kernel<<<dim3(gfill + gconv + gwt + 1), dim3(256), 0, stream>>>(
        src, dst, perm, rowptr, E, x, dinv, N, W2a, W2b,
        col, xh, Wta, Wtb, a0 + (size_t)HUB * FD, gfill, gconv, gwt);

    int pullG = (N + 15) / 16;
    int  gemmG = (N + 63) / 64;
    dim3 gemmB(24, 8);

    // layer 1 (pull + hub merged; hub accumulates into a0's hub row)
    pull_hub32<<<dim3(pullG + 128), dim3(384), 0, stream>>>(
        xh, dinv, rowptr, col, N, HUB, pullG, a0, a0 + (size_t)HUB * FD);
    gemm96_h  <<<dim3(gemmG), gemmB, 0, stream>>>(a0, W1, b1, dinv, h1h, N);

    // layer 2 (pull16 + hub merged; hub row delivered to mfma via hubacc)
    pull_hub16<<<dim3(pullG + 128), dim3(384), 0, stream>>>(
        h1h, dinv, rowptr, col, N, HUB, pullG, (int2*)a1h, hubacc);
    mfma_dual <<<dim3(gemmG), dim3(256), 0, stream>>>(a1h, hubacc, Wta, Wtb,
                                                      b2a, b2b, mu_slot, ls_slot,
                                                      N, HUB);
}

// Round 5
// 260.022 us; speedup vs baseline: 1.2842x; 1.0190x over previous
//
#include <hip/hip_runtime.h>
#include <hip/hip_fp16.h>

#define FD 96        // feature dim
#define COL_CAP 2048 // LDS col staging capacity (32 rows, avg ~18 edges; only
                     // the block containing HUB (~50K edges) overflows)

typedef _Float16 f16x8 __attribute__((ext_vector_type(8)));
typedef float f32x4 __attribute__((ext_vector_type(4)));

// ---- fp16 pack/unpack helpers ---------------------------------------------
__device__ inline float2 unpack2(int v) {
    __half2 h = *reinterpret_cast<__half2*>(&v);
    return __half22float2(h);
}
__device__ inline int2 pack4(float a, float b, float c, float d) {
    __half2 lo = __floats2half2_rn(a, b);
    __half2 hi = __floats2half2_rn(c, d);
    int2 r;
    r.x = *reinterpret_cast<int*>(&lo);
    r.y = *reinterpret_cast<int*>(&hi);
    return r;
}
// pack 8 fp32 -> f16x8 with pack4 rounding (== pack_hub path)
__device__ inline f16x8 pack8h(const float* __restrict__ h) {
    int2 a = pack4(h[0], h[1], h[2], h[3]);
    int2 b = pack4(h[4], h[5], h[6], h[7]);
    int4 r = make_int4(a.x, a.y, b.x, b.y);
    return *reinterpret_cast<f16x8*>(&r);
}
// load 4 fp16 (int2) from LDS -> float4
__device__ inline float4 lds_w4(const __half* Wl, int k, int c4) {
    int2 wv = *(const int2*)&Wl[k * FD + c4];
    float2 lo = unpack2(wv.x), hi = unpack2(wv.y);
    return make_float4(lo.x, lo.y, hi.x, hi.y);
}

// ---- 8-unroll aggregation over a HALF-TABLE (stride 12 int2 per row).
// c in 0..11 selects the 4-feature group; arithmetic order identical to the
// verified round-0/round-4 pull kernels (same int2 granularity, same pairwise
// tree, same tail). COLX(e) supplies the source index.
#define AGG12_BODY(COLX)                                                      \
    float ax = 0.f, ay = 0.f, az = 0.f, aw = 0.f;                             \
    int e = beg;                                                              \
    for (; e + 8 <= end; e += 8) {                                            \
        int s0 = COLX(e + 0), s1 = COLX(e + 1), s2 = COLX(e + 2), s3 = COLX(e + 3); \
        int s4 = COLX(e + 4), s5 = COLX(e + 5), s6 = COLX(e + 6), s7 = COLX(e + 7); \
        int2 r0 = fh[(long)s0 * 12 + c], r1 = fh[(long)s1 * 12 + c];          \
        int2 r2 = fh[(long)s2 * 12 + c], r3 = fh[(long)s3 * 12 + c];          \
        int2 r4 = fh[(long)s4 * 12 + c], r5 = fh[(long)s5 * 12 + c];          \
        int2 r6 = fh[(long)s6 * 12 + c], r7 = fh[(long)s7 * 12 + c];          \
        float2 l0 = unpack2(r0.x), h0 = unpack2(r0.y);                        \
        float2 l1 = unpack2(r1.x), h1_ = unpack2(r1.y);                       \
        float2 l2 = unpack2(r2.x), h2 = unpack2(r2.y);                        \
        float2 l3 = unpack2(r3.x), h3 = unpack2(r3.y);                        \
        float2 l4 = unpack2(r4.x), h4 = unpack2(r4.y);                        \
        float2 l5 = unpack2(r5.x), h5 = unpack2(r5.y);                        \
        float2 l6 = unpack2(r6.x), h6 = unpack2(r6.y);                        \
        float2 l7 = unpack2(r7.x), h7 = unpack2(r7.y);                        \
        ax += (l0.x + l1.x) + (l2.x + l3.x) + (l4.x + l5.x) + (l6.x + l7.x);  \
        ay += (l0.y + l1.y) + (l2.y + l3.y) + (l4.y + l5.y) + (l6.y + l7.y);  \
        az += (h0.x + h1_.x) + (h2.x + h3.x) + (h4.x + h5.x) + (h6.x + h7.x); \
        aw += (h0.y + h1_.y) + (h2.y + h3.y) + (h4.y + h5.y) + (h6.y + h7.y); \
    }                                                                         \
    for (; e < end; e++) {                                                    \
        int s = COLX(e);                                                      \
        int2 r = fh[(long)s * 12 + c];                                        \
        float2 lo = unpack2(r.x), hi = unpack2(r.y);                          \
        ax += lo.x; ay += lo.y; az += hi.x; aw += hi.y;                       \
    }

__device__ inline float4 agg12_glb(const int2* __restrict__ fh,
                                   const int* __restrict__ col,
                                   int beg, int end, int c) {
    #define COLG(E) col[E]
    AGG12_BODY(COLG)
    #undef COLG
    return make_float4(ax, ay, az, aw);
}
__device__ inline float4 agg12_lds(const int2* __restrict__ fh,
                                   const int* colS, int beg, int end, int c) {
    #define COLS(E) colS[E]
    AGG12_BODY(COLS)
    #undef COLS
    return make_float4(ax, ay, az, aw);
}

// ---------------------------------------------------------------------------
// K1: degree histogram + per-edge rank capture (perm). Hub via ballot.
// ---------------------------------------------------------------------------
__global__ void deg_kernel(const int* __restrict__ dst, int E, int HUB,
                           int* __restrict__ counts, int* __restrict__ perm) {
    int e = blockIdx.x * 256 + threadIdx.x;
    int d = (e < E) ? dst[e] : -1;
    bool isHub = (d == HUB);
    unsigned long long m = __ballot(isHub);
    if (isHub) {
        int lane = threadIdx.x & 63;
        int leader = __ffsll((unsigned long long)m) - 1;
        int base = 0;
        if (lane == leader) base = atomicAdd(&counts[HUB], (int)__popcll(m));
        base = __shfl(base, leader);
        unsigned long long below = m & ((1ull << lane) - 1ull);
        perm[e] = base + (int)__popcll(below);
    } else if (d >= 0) {
        perm[e] = atomicAdd(&counts[d], 1);
    }
}

// ---------------------------------------------------------------------------
// K2: single-kernel scan. Block b brute-force sums counts[0..b*1024), then
// scans its own 1024-chunk. Emits rowptr[0..N] and dinv (fused).
// ---------------------------------------------------------------------------
__global__ __launch_bounds__(1024)
void scan_kernel(const int* __restrict__ counts, int N,
                 int* __restrict__ rowptr, float* __restrict__ dinv) {
    int t = threadIdx.x, lane = t & 63, wv = t >> 6;
    int base = blockIdx.x * 1024;
    int pre = 0;
    for (int idx = t; idx < base; idx += 1024) pre += counts[idx];
    #pragma unroll
    for (int off = 32; off; off >>= 1) pre += __shfl_down(pre, off);
    __shared__ int wsA[16];
    __shared__ int preS;
    if (lane == 0) wsA[wv] = pre;
    __syncthreads();
    if (t == 0) {
        int s = 0;
        #pragma unroll
        for (int k = 0; k < 16; k++) s += wsA[k];
        preS = s;
    }
    __syncthreads();
    int blockpre = preS;
    int i = base + t;
    int v = (i < N) ? counts[i] : 0;
    int x = v;
    #pragma unroll
    for (int off = 1; off < 64; off <<= 1) {
        int u = __shfl_up(x, off);
        if (lane >= off) x += u;
    }
    __shared__ int wsum[16];
    if (lane == 63) wsum[wv] = x;
    __syncthreads();
    if (wv == 0 && lane < 16) {
        int w = wsum[lane];
        #pragma unroll
        for (int off = 1; off < 16; off <<= 1) {
            int u = __shfl_up(w, off);
            if (lane >= off) w += u;
        }
        wsum[lane] = w;
    }
    __syncthreads();
    int waveoff = (wv == 0) ? 0 : wsum[wv - 1];
    if (i <= N) rowptr[i] = blockpre + waveoff + x - v;
    if (i < N) {
        float d = (float)v;
        dinv[i] = (d > 0.f) ? rsqrtf(fmaxf(d, 1.f)) : 0.f;
    }
}

// ---------------------------------------------------------------------------
// K3: prep — fused {CSR col fill} + {xh halves = fp16(dinv*x)} + {Wt convert}
// + {zero a0 hub row}. xh is split into two compact half-tables (48 feats
// each, 4.8 MB) so each pull pass has an L2-sized working set.
// ---------------------------------------------------------------------------
__global__ __launch_bounds__(256)
void prep_kernel(const int* __restrict__ src, const int* __restrict__ dst,
                 const int* __restrict__ perm, const int* __restrict__ rowptr,
                 int E,
                 const float* __restrict__ x, const float* __restrict__ dinv,
                 int N,
                 const float* __restrict__ W2a, const float* __restrict__ W2b,
                 int* __restrict__ col,
                 int2* __restrict__ xhL, int2* __restrict__ xhH,
                 __half* __restrict__ Wta, __half* __restrict__ Wtb,
                 float* __restrict__ a0hub, int gfill, int gconv, int gwt) {
    int b = blockIdx.x;
    if (b < gfill) {
        int e = b * 256 + threadIdx.x;
        if (e >= E) return;
        int d = dst[e];
        col[rowptr[d] + perm[e]] = src[e];
    } else if (b < gfill + gconv) {
        int i = (b - gfill) * 256 + threadIdx.x;
        if (i >= N * 24) return;
        int n = i / 24, g = i % 24;
        float dn = dinv[n];
        float4 a = ((const float4*)x)[i];
        int2 v = pack4(a.x * dn, a.y * dn, a.z * dn, a.w * dn);
        if (g < 12) xhL[(long)n * 12 + g] = v;
        else        xhH[(long)n * 12 + g - 12] = v;
    } else if (b < gfill + gconv + gwt) {
        int i = (b - gfill - gconv) * 256 + threadIdx.x;
        if (i >= FD * FD) return;
        int n = i / FD, k = i % FD;
        Wta[i] = __float2half(W2a[k * FD + n]);
        Wtb[i] = __float2half(W2b[k * FD + n]);
    } else {
        int i = threadIdx.x;
        if (i < FD) a0hub[i] = 0.f;
    }
}

// ---------------------------------------------------------------------------
// Merged half-table pull+hub kernels. Grid = 2*G + 128; block 384 = (c 0..11,
// y 0..31).
//   blocks [0, G):    lo-half pull, 32 rows/block, col span staged in LDS
//   blocks [G, 2G):   hi-half pull (runs after lo drains -> L2 sees 4.8 MB)
//   blocks [2G,2G+64):   lo-half hub, 32 streams/block (2048 total = same
//                        edge chunking as round-4 -> identical partials)
//   blocks [2G+64,2G+128): hi-half hub
// ---------------------------------------------------------------------------
__global__ __launch_bounds__(384)
void pull_hub32(const int2* __restrict__ fhL, const int2* __restrict__ fhH,
                const float* __restrict__ dinv,
                const int* __restrict__ rowptr, const int* __restrict__ col,
                int N, int HUB, int G,
                float* __restrict__ out, float* __restrict__ hubdest) {
    __shared__ int colS[COL_CAP];
    __shared__ float4 red[32][12];
    int t = threadIdx.x;
    int c = t % 12, y = t / 12;
    int b = blockIdx.x;
    if (b < 2 * G) {
        const int2* fh = (b < G) ? fhL : fhH;
        int foff = (b < G) ? 0 : 12;
        int bb = (b < G) ? b : b - G;
        int n0 = bb * 32;
        int nend = min(n0 + 32, N);
        int beg0 = rowptr[n0];
        int span = rowptr[nend] - beg0;
        bool staged = (span <= COL_CAP);
        if (staged) {
            for (int i = t; i < span; i += 384) colS[i] = col[beg0 + i];
            __syncthreads();
        }
        int n = n0 + y;
        if (n < N && n != HUB) {
            int beg = rowptr[n], end = rowptr[n + 1];
            float4 a = staged ? agg12_lds(fh, colS, beg - beg0, end - beg0, c)
                              : agg12_glb(fh, col, beg, end, c);
            float dn = dinv[n];
            ((float4*)out)[(long)n * 24 + foff + c] =
                make_float4(a.x * dn, a.y * dn, a.z * dn, a.w * dn);
        }
    } else {
        int hb = b - 2 * G;
        const int2* fh = (hb < 64) ? fhL : fhH;
        int foff = (hb < 64) ? 0 : 12;
        int bb = (hb < 64) ? hb : hb - 64;
        int beg = rowptr[HUB], end = rowptr[HUB + 1];
        int deg = end - beg;
        int chunk = (deg + 2047) / 2048;
        int sid = bb * 32 + y;
        int e = beg + sid * chunk;
        int e1 = min(e + chunk, end);
        float ax = 0.f, ay = 0.f, az = 0.f, aw = 0.f;
        for (; e + 4 <= e1; e += 4) {
            int s0 = col[e + 0], s1 = col[e + 1], s2 = col[e + 2], s3 = col[e + 3];
            int2 r0 = fh[(long)s0 * 12 + c], r1 = fh[(long)s1 * 12 + c];
            int2 r2 = fh[(long)s2 * 12 + c], r3 = fh[(long)s3 * 12 + c];
            float2 l0 = unpack2(r0.x), h0 = unpack2(r0.y);
            float2 l1 = unpack2(r1.x), h1_ = unpack2(r1.y);
            float2 l2 = unpack2(r2.x), h2 = unpack2(r2.y);
            float2 l3 = unpack2(r3.x), h3 = unpack2(r3.y);
            ax += (l0.x + l1.x) + (l2.x + l3.x);
            ay += (l0.y + l1.y) + (l2.y + l3.y);
            az += (h0.x + h1_.x) + (h2.x + h3.x);
            aw += (h0.y + h1_.y) + (h2.y + h3.y);
        }
        for (; e < e1; e++) {
            int s = col[e];
            int2 r = fh[(long)s * 12 + c];
            float2 lo = unpack2(r.x), hi = unpack2(r.y);
            ax += lo.x; ay += lo.y; az += hi.x; aw += hi.y;
        }
        red[y][c] = make_float4(ax, ay, az, aw);
        __syncthreads();
        if (y == 0) {
            float4 tt = red[0][c];
            #pragma unroll
            for (int k = 1; k < 32; k++) {
                float4 u = red[k][c];
                tt.x += u.x; tt.y += u.y; tt.z += u.z; tt.w += u.w;
            }
            float dh = dinv[HUB];
            float* o = hubdest + (foff + c) * 4;
            unsafeAtomicAdd(o + 0, tt.x * dh);
            unsafeAtomicAdd(o + 1, tt.y * dh);
            unsafeAtomicAdd(o + 2, tt.z * dh);
            unsafeAtomicAdd(o + 3, tt.w * dh);
        }
    }
}

__global__ __launch_bounds__(384)
void pull_hub16(const int2* __restrict__ fhL, const int2* __restrict__ fhH,
                const float* __restrict__ dinv,
                const int* __restrict__ rowptr, const int* __restrict__ col,
                int N, int HUB, int G,
                int2* __restrict__ out16, float* __restrict__ hubdest) {
    __shared__ int colS[COL_CAP];
    __shared__ float4 red[32][12];
    int t = threadIdx.x;
    int c = t % 12, y = t / 12;
    int b = blockIdx.x;
    if (b < 2 * G) {
        const int2* fh = (b < G) ? fhL : fhH;
        int foff = (b < G) ? 0 : 12;
        int bb = (b < G) ? b : b - G;
        int n0 = bb * 32;
        int nend = min(n0 + 32, N);
        int beg0 = rowptr[n0];
        int span = rowptr[nend] - beg0;
        bool staged = (span <= COL_CAP);
        if (staged) {
            for (int i = t; i < span; i += 384) colS[i] = col[beg0 + i];
            __syncthreads();
        }
        int n = n0 + y;
        if (n < N && n != HUB) {
            int beg = rowptr[n], end = rowptr[n + 1];
            float4 a = staged ? agg12_lds(fh, colS, beg - beg0, end - beg0, c)
                              : agg12_glb(fh, col, beg, end, c);
            float dn = dinv[n];
            out16[(long)n * 24 + foff + c] =
                pack4(a.x * dn, a.y * dn, a.z * dn, a.w * dn);
        }
    } else {
        int hb = b - 2 * G;
        const int2* fh = (hb < 64) ? fhL : fhH;
        int foff = (hb < 64) ? 0 : 12;
        int bb = (hb < 64) ? hb : hb - 64;
        int beg = rowptr[HUB], end = rowptr[HUB + 1];
        int deg = end - beg;
        int chunk = (deg + 2047) / 2048;
        int sid = bb * 32 + y;
        int e = beg + sid * chunk;
        int e1 = min(e + chunk, end);
        float ax = 0.f, ay = 0.f, az = 0.f, aw = 0.f;
        for (; e + 4 <= e1; e += 4) {
            int s0 = col[e + 0], s1 = col[e + 1], s2 = col[e + 2], s3 = col[e + 3];
            int2 r0 = fh[(long)s0 * 12 + c], r1 = fh[(long)s1 * 12 + c];
            int2 r2 = fh[(long)s2 * 12 + c], r3 = fh[(long)s3 * 12 + c];
            float2 l0 = unpack2(r0.x), h0 = unpack2(r0.y);
            float2 l1 = unpack2(r1.x), h1_ = unpack2(r1.y);
            float2 l2 = unpack2(r2.x), h2 = unpack2(r2.y);
            float2 l3 = unpack2(r3.x), h3 = unpack2(r3.y);
            ax += (l0.x + l1.x) + (l2.x + l3.x);
            ay += (l0.y + l1.y) + (l2.y + l3.y);
            az += (h0.x + h1_.x) + (h2.x + h3.x);
            aw += (h0.y + h1_.y) + (h2.y + h3.y);
        }
        for (; e < e1; e++) {
            int s = col[e];
            int2 r = fh[(long)s * 12 + c];
            float2 lo = unpack2(r.x), hi = unpack2(r.y);
            ax += lo.x; ay += lo.y; az += hi.x; aw += hi.y;
        }
        red[y][c] = make_float4(ax, ay, az, aw);
        __syncthreads();
        if (y == 0) {
            float4 tt = red[0][c];
            #pragma unroll
            for (int k = 1; k < 32; k++) {
                float4 u = red[k][c];
                tt.x += u.x; tt.y += u.y; tt.z += u.z; tt.w += u.w;
            }
            float dh = dinv[HUB];
            float* o = hubdest + (foff + c) * 4;
            unsafeAtomicAdd(o + 0, tt.x * dh);
            unsafeAtomicAdd(o + 1, tt.y * dh);
            unsafeAtomicAdd(o + 2, tt.z * dh);
            unsafeAtomicAdd(o + 3, tt.w * dh);
        }
    }
}

// ---------------------------------------------------------------------------
// K7: gemm96_h — h1 halves = fp16(dinv*relu(A@W1+b1)). W staged fp16 in LDS.
// Output split into lo/hi half-tables for the layer-2 pull.
// ---------------------------------------------------------------------------
__global__ __launch_bounds__(192)
void gemm96_h(const float* __restrict__ A, const float* __restrict__ W,
              const float* __restrict__ bias, const float* __restrict__ dinv,
              int2* __restrict__ outL, int2* __restrict__ outH, int N) {
    __shared__ __half Wl[FD * FD];       // 18432 B
    __shared__ float As[64 * 100];       // 25600 B
    int t = threadIdx.y * 24 + threadIdx.x;
    {   // stage W fp32 -> fp16
        const float4* W4 = (const float4*)W;
        #pragma unroll 4
        for (int i = t; i < FD * 24; i += 192) {
            float4 w = W4[i];
            *(int2*)&Wl[i * 4] = pack4(w.x, w.y, w.z, w.w);
        }
    }
    int row0 = blockIdx.x * 64;
    int nrows = min(64, N - row0);
    {
        const float4* A4 = (const float4*)(A + (long)row0 * FD);
        for (int i = t; i < nrows * 24; i += 192) {
            int r = i / 24, g = i % 24;
            *(float4*)&As[r * 100 + g * 4] = A4[i];
        }
    }
    __syncthreads();
    int c = threadIdx.x, y = threadIdx.y;
    float acc[8][4];
    #pragma unroll
    for (int j = 0; j < 8; j++)
        #pragma unroll
        for (int i = 0; i < 4; i++) acc[j][i] = 0.f;
    for (int kk = 0; kk < FD; kk += 4) {
        float4 w0 = lds_w4(Wl, kk + 0, 4 * c);
        float4 w1 = lds_w4(Wl, kk + 1, 4 * c);
        float4 w2 = lds_w4(Wl, kk + 2, 4 * c);
        float4 w3 = lds_w4(Wl, kk + 3, 4 * c);
        #pragma unroll
        for (int j = 0; j < 8; j++) {
            float4 a = *(const float4*)&As[(y + 8 * j) * 100 + kk];
            acc[j][0] = fmaf(a.x, w0.x, fmaf(a.y, w1.x, fmaf(a.z, w2.x, fmaf(a.w, w3.x, acc[j][0]))));
            acc[j][1] = fmaf(a.x, w0.y, fmaf(a.y, w1.y, fmaf(a.z, w2.y, fmaf(a.w, w3.y, acc[j][1]))));
            acc[j][2] = fmaf(a.x, w0.z, fmaf(a.y, w1.z, fmaf(a.z, w2.z, fmaf(a.w, w3.z, acc[j][2]))));
            acc[j][3] = fmaf(a.x, w0.w, fmaf(a.y, w1.w, fmaf(a.z, w2.w, fmaf(a.w, w3.w, acc[j][3]))));
        }
    }
    float4 b4 = *(const float4*)&bias[4 * c];
    #pragma unroll
    for (int j = 0; j < 8; j++) {
        int r = y + 8 * j;
        if (r < nrows) {
            float vx = fmaxf(acc[j][0] + b4.x, 0.f);
            float vy = fmaxf(acc[j][1] + b4.y, 0.f);
            float vz = fmaxf(acc[j][2] + b4.z, 0.f);
            float vw = fmaxf(acc[j][3] + b4.w, 0.f);
            float dr = dinv[row0 + r];
            int2 v = pack4(vx * dr, vy * dr, vz * dr, vw * dr);
            long n = row0 + r;
            if (c < 12) outL[n * 12 + c] = v;
            else        outH[n * 12 + c - 12] = v;
        }
    }
}

// ---------------------------------------------------------------------------
// K8: mfma_dual — mu = A@Wa+ba, ls = A@Wb+bb via v_mfma_f32_16x16x32_f16.
// Lanes whose row == HUB synthesize A-fragments from hubacc (fp32) with
// pack4 rounding.
// ---------------------------------------------------------------------------
__global__ __launch_bounds__(256)
void mfma_dual(const __half* __restrict__ a1h, const float* __restrict__ hubacc,
               const __half* __restrict__ Wta, const __half* __restrict__ Wtb,
               const float* __restrict__ ba, const float* __restrict__ bb,
               float* __restrict__ mu, float* __restrict__ ls, int N, int HUB) {
    __shared__ __half WtaL[FD * FD];     // 18432 B
    __shared__ __half WtbL[FD * FD];     // 18432 B
    int t = threadIdx.x;
    {
        const int4* sa = (const int4*)Wta;
        const int4* sb = (const int4*)Wtb;
        int4* da = (int4*)WtaL;
        int4* db = (int4*)WtbL;
        #pragma unroll
        for (int i = t; i < FD * FD / 8; i += 256) { da[i] = sa[i]; db[i] = sb[i]; }
    }
    __syncthreads();
    int wv = t >> 6, lane = t & 63;
    int m = lane & 15, q = lane >> 4;
    long row0 = (long)blockIdx.x * 64 + wv * 16;

    const f16x8* arow = (const f16x8*)&a1h[(row0 + m) * FD + q * 8];
    f16x8 A0 = arow[0];
    f16x8 A1 = arow[4];
    f16x8 A2 = arow[8];
    if (row0 + m == HUB) {   // hub row: a1h[HUB] never written; build from fp32
        A0 = pack8h(hubacc + q * 8);
        A1 = pack8h(hubacc + 32 + q * 8);
        A2 = pack8h(hubacc + 64 + q * 8);
    }

    #pragma unroll
    for (int nt = 0; nt < 6; nt++) {
        int n0 = nt * 16;
        const f16x8* brA = (const f16x8*)&WtaL[(n0 + m) * FD + q * 8];
        const f16x8* brB = (const f16x8*)&WtbL[(n0 + m) * FD + q * 8];
        f32x4 acca = {0.f, 0.f, 0.f, 0.f};
        f32x4 accb = {0.f, 0.f, 0.f, 0.f};
        acca = __builtin_amdgcn_mfma_f32_16x16x32_f16(A0, brA[0], acca, 0, 0, 0);
        acca = __builtin_amdgcn_mfma_f32_16x16x32_f16(A1, brA[4], acca, 0, 0, 0);
        acca = __builtin_amdgcn_mfma_f32_16x16x32_f16(A2, brA[8], acca, 0, 0, 0);
        accb = __builtin_amdgcn_mfma_f32_16x16x32_f16(A0, brB[0], accb, 0, 0, 0);
        accb = __builtin_amdgcn_mfma_f32_16x16x32_f16(A1, brB[4], accb, 0, 0, 0);
        accb = __builtin_amdgcn_mfma_f32_16x16x32_f16(A2, brB[8], accb, 0, 0, 0);
        float bva = ba[n0 + m];
        float bvb = bb[n0 + m];
        #pragma unroll
        for (int r = 0; r < 4; r++) {
            long row = row0 + q * 4 + r;
            if (row < N) {
                mu[row * FD + n0 + m] = acca[r] + bva;
                ls[row * FD + n0 + m] = accb[r] + bvb;
            }
        }
    }
}

// ---------------------------------------------------------------------------
// Launch. 8 dispatches: memset, deg, scan, prep, pull_hub32, gemm96_h,
// pull_hub16, mfma_dual. Feature tables split into 4.8 MB halves so each
// pull pass has an L2-per-XCD-sized working set.
//   xhL|xhH  = fp16(dinv*x) halves   -> mu slot, lower 9.6 MB
//   a0       = agg(xh)               -> ls slot (fp32; hub row pre-zeroed)
//   h1L|h1H  = fp16 layer-1 halves   -> mu slot, upper 9.6 MB  (a0 dead)
//   a1h      = fp16 agg(h1) full-row -> ws (hub row via hubacc in mfma_dual)
//   mu,ls    = MFMA dual-gemm(a1h)   -> d_out (xh,h1,a0 all dead)
// ws: [counts N][hubacc 96][perm E][rowptr N+1][col E][dinv N]
//     [Wta][Wtb][a1h (N+64)x96 h]  ~= 17.5 MB
// ---------------------------------------------------------------------------
extern "C" void kernel_launch(void* const* d_in, const int* in_sizes, int n_in,
                              void* d_out, int out_size, void* d_ws, size_t ws_size,
                              hipStream_t stream) {
    const float* x   = (const float*)d_in[0];
    const float* W1  = (const float*)d_in[1];
    const float* b1  = (const float*)d_in[2];
    const float* W2a = (const float*)d_in[3];
    const float* b2a = (const float*)d_in[4];
    const float* W2b = (const float*)d_in[5];
    const float* b2b = (const float*)d_in[6];
    const int*   ei  = (const int*)d_in[7];

    const int N   = in_sizes[0] / FD;
    const int E   = in_sizes[7] / 2;
    const int HUB = N - 1;
    const int* src = ei;
    const int* dst = ei + E;
    const int NB  = (N + 1023) / 1024;

    int* counts   = (int*)d_ws;                 // N
    float* hubacc = (float*)(counts + N);       // 96
    int* perm     = (int*)(hubacc + FD);        // E
    int* rowptr   = perm + E;                   // N+1
    int* col      = rowptr + (N + 1);           // E
    float* dinv   = (float*)(col + E);          // N
    uintptr_t p = (uintptr_t)(dinv + N);
    p = (p + 15) & ~(uintptr_t)15;
    __half* Wta = (__half*)p;                   // FD*FD
    __half* Wtb = Wta + FD * FD;                // FD*FD
    __half* a1h = Wtb + FD * FD;                // (N+64)*FD halves, 16B-aligned

    float* mu_slot = (float*)d_out;
    float* ls_slot = (float*)d_out + (size_t)N * FD;
    int2* xhL = (int2*)mu_slot;                      // 4.8 MB
    int2* xhH = xhL + (size_t)N * 12;                // 4.8 MB
    int2* h1L = (int2*)mu_slot + (size_t)N * 24;     // 4.8 MB
    int2* h1H = h1L + (size_t)N * 12;                // 4.8 MB
    float* a0 = ls_slot;

    // zero counts + hubacc (contiguous)
    (void)hipMemsetAsync(counts, 0, ((size_t)N + FD) * sizeof(int), stream);

    deg_kernel <<<dim3((E + 255) / 256), dim3(256), 0, stream>>>(dst, E, HUB,
                                                                 counts, perm);
    scan_kernel<<<dim3(NB), dim3(1024), 0, stream>>>(counts, N, rowptr, dinv);

    int gfill = (E + 255) / 256;
    int gconv = (N * 24 + 255) / 256;
    int gwt   = (FD * FD + 255) / 256;
    prep_kernel<<<dim3(gfill + gconv + gwt + 1), dim3(256), 0, stream>>>(
        src, dst, perm, rowptr, E, x, dinv, N, W2a, W2b,
        col, xhL, xhH, Wta, Wtb, a0 + (size_t)HUB * FD, gfill, gconv, gwt);

    int G = (N + 31) / 32;
    int gemmG = (N + 63) / 64;
    dim3 gemmB(24, 8);

    // layer 1 (half-table pulls + hub merged; hub accumulates into a0 hub row)
    pull_hub32<<<dim3(2 * G + 128), dim3(384), 0, stream>>>(
        xhL, xhH, dinv, rowptr, col, N, HUB, G, a0, a0 + (size_t)HUB * FD);
    gemm96_h  <<<dim3(gemmG), gemmB, 0, stream>>>(a0, W1, b1, dinv, h1L, h1H, N);

    // layer 2 (half-table pulls + hub merged; hub row via hubacc in mfma)
    pull_hub16<<<dim3(2 * G + 128), dim3(384), 0, stream>>>(
        h1L, h1H, dinv, rowptr, col, N, HUB, G, (int2*)a1h, hubacc);
    mfma_dual <<<dim3(gemmG), dim3(256), 0, stream>>>(a1h, hubacc, Wta, Wtb,
                                                      b2a, b2b, mu_slot, ls_slot,
                                                      N, HUB);
}